// Round 9
// baseline (231.483 us; speedup 1.0000x reference)
//
#include <hip/hip_runtime.h>
#include <math.h>

namespace {

constexpr int B = 8, D = 49, C = 512, N = 12, H = 256, E = 144;
constexpr int M_BD  = B * D;        // 392
constexpr int M_BND = B * N * D;    // 4704
constexpr float BN_EPS = 1e-5f;
constexpr float ATT_SCALE = 0.0625f; // (C/2)^-0.5

typedef __attribute__((ext_vector_type(4))) float  floatx4;
typedef __attribute__((ext_vector_type(8))) short  shortx8;

__device__ inline unsigned short f2bf(float f) {
  unsigned u = __float_as_uint(f);
  return (unsigned short)((u + 0x7fffu + ((u >> 16) & 1u)) >> 16);
}
__device__ inline float bf2f(unsigned short u) {
  return __uint_as_float(((unsigned)u) << 16);
}

__device__ inline void gload16(const unsigned short* g, unsigned short* l) {
  __builtin_amdgcn_global_load_lds(
      (const __attribute__((address_space(1))) void*)g,
      (__attribute__((address_space(3))) void*)l, 16, 0, 0);
}

// ------- tcast (z<28): fp32 [512][Nn] -> bf16 [Nn][512]; z==28: castrow/bias/b2 -------
struct TCJobs {
  const float* src[28];
  unsigned short* dst[28];
  int nn[28];
};

__global__ __launch_bounds__(256)
void tcast_k(TCJobs jobs,
             const float* __restrict__ x, unsigned short* __restrict__ xb,
             const float* __restrict__ awv, unsigned short* __restrict__ armwvb,
             const float* __restrict__ bk, const float* __restrict__ bv,
             const float* __restrict__ bq2, const float* __restrict__ bk2,
             const float* __restrict__ arm_bv, const float* __restrict__ epw,
             const float* __restrict__ epb,
             float* __restrict__ kvbias, float* __restrict__ qkvbias)
{
  const int z = blockIdx.z;
  const int tid = threadIdx.x;
  if (z == 28) {
    int idx = (blockIdx.y * 16 + blockIdx.x) * 256 + tid;
    const int n1 = M_BD * C / 8;            // 25088
    const int n2 = n1 + C * C / 8;          // 57856
    if (idx < n1) {
      int i8 = idx * 8;
      float4 a = *reinterpret_cast<const float4*>(x + i8);
      float4 b = *reinterpret_cast<const float4*>(x + i8 + 4);
      shortx8 o;
      o[0]=(short)f2bf(a.x); o[1]=(short)f2bf(a.y); o[2]=(short)f2bf(a.z); o[3]=(short)f2bf(a.w);
      o[4]=(short)f2bf(b.x); o[5]=(short)f2bf(b.y); o[6]=(short)f2bf(b.z); o[7]=(short)f2bf(b.w);
      *reinterpret_cast<shortx8*>(xb + i8) = o;
    } else if (idx < n2) {
      int i8 = (idx - n1) * 8;
      float4 a = *reinterpret_cast<const float4*>(awv + i8);
      float4 b = *reinterpret_cast<const float4*>(awv + i8 + 4);
      shortx8 o;
      o[0]=(short)f2bf(a.x); o[1]=(short)f2bf(a.y); o[2]=(short)f2bf(a.z); o[3]=(short)f2bf(a.w);
      o[4]=(short)f2bf(b.x); o[5]=(short)f2bf(b.y); o[6]=(short)f2bf(b.z); o[7]=(short)f2bf(b.w);
      *reinterpret_cast<shortx8*>(armwvb + i8) = o;
    } else if (idx >= 58112 && idx < 58624) {
      int c = idx - 58112;
      float s = epb[c];
      for (int k = 0; k < C; ++k) s = fmaf(arm_bv[k], epw[k * C + c], s);
      qkvbias[512 + c] = s;
    }
    if (idx < 256) { kvbias[idx] = bk[idx]; qkvbias[idx] = bq2[idx]; qkvbias[256 + idx] = bk2[idx]; }
    if (idx < 512) kvbias[256 + idx] = bv[idx];
    return;
  }
  const float* src = jobs.src[z];
  unsigned short* dst = jobs.dst[z];
  const int Nn = jobs.nn[z];
  const int tx = blockIdx.x, ty = blockIdx.y;
  if (tx * 32 >= Nn) return;
  __shared__ float t[32][33];
  const int lr = tid >> 5, lc = tid & 31;
#pragma unroll
  for (int p = 0; p < 4; ++p) {
    int k = ty * 32 + p * 8 + lr;
    t[p * 8 + lr][lc] = src[(long long)k * Nn + tx * 32 + lc];
  }
  __syncthreads();
#pragma unroll
  for (int p = 0; p < 4; ++p) {
    int n = tx * 32 + p * 8 + lr;
    dst[(long long)n * 512 + ty * 32 + lc] = f2bf(t[lc][p * 8 + lr]);
  }
}

// ---------------- 64x64-tile bf16 MFMA GEMM body ----------------
__device__ __forceinline__
void gemm64_body(const void* __restrict__ Ain, const unsigned short* __restrict__ Bt,
                 const float* __restrict__ bp, float* __restrict__ co,
                 unsigned short* __restrict__ cb,
                 int M, int Nn, int K, int lda, int ldb, int ldc, int abf,
                 int bx, int by)
{
  const float* Af = abf ? nullptr : (const float*)Ain;
  const unsigned short* Ab = abf ? (const unsigned short*)Ain : nullptr;

  __shared__ short As[64 * 72];
  __shared__ short Bs[64 * 72];

  const int tid = threadIdx.x;
  const int row0 = bx * 64, col0 = by * 64;
  const int wid = tid >> 6, lane = tid & 63;
  const int wr = wid >> 1, wc = wid & 1;
  const int lr = lane & 15, lg = lane >> 4;

  floatx4 acc00 = {0.f,0.f,0.f,0.f}, acc01 = {0.f,0.f,0.f,0.f};
  floatx4 acc10 = {0.f,0.f,0.f,0.f}, acc11 = {0.f,0.f,0.f,0.f};

  const int r = tid >> 2, seg = tid & 3;
  const int gr = row0 + r, gn = col0 + r;
  short* aw = &As[r * 72 + seg * 16];
  short* bw = &Bs[r * 72 + seg * 16];
  const shortx8 zz = {0,0,0,0,0,0,0,0};

  for (int k0 = 0; k0 < K; k0 += 64) {
    shortx8 w0, w1;
    if (gr < M) {
      if (abf) {
        const shortx8* ap = reinterpret_cast<const shortx8*>(Ab + (long long)gr * lda + seg * 16 + k0);
        w0 = ap[0]; w1 = ap[1];
      } else {
        const float4* ap = reinterpret_cast<const float4*>(Af + (long long)gr * lda + seg * 16 + k0);
        float4 fa0 = ap[0], fa1 = ap[1], fa2 = ap[2], fa3 = ap[3];
        w0[0]=(short)f2bf(fa0.x); w0[1]=(short)f2bf(fa0.y); w0[2]=(short)f2bf(fa0.z); w0[3]=(short)f2bf(fa0.w);
        w0[4]=(short)f2bf(fa1.x); w0[5]=(short)f2bf(fa1.y); w0[6]=(short)f2bf(fa1.z); w0[7]=(short)f2bf(fa1.w);
        w1[0]=(short)f2bf(fa2.x); w1[1]=(short)f2bf(fa2.y); w1[2]=(short)f2bf(fa2.z); w1[3]=(short)f2bf(fa2.w);
        w1[4]=(short)f2bf(fa3.x); w1[5]=(short)f2bf(fa3.y); w1[6]=(short)f2bf(fa3.z); w1[7]=(short)f2bf(fa3.w);
      }
    } else { w0 = zz; w1 = zz; }
    const shortx8* bp8 = reinterpret_cast<const shortx8*>(Bt + (long long)gn * ldb + seg * 16 + k0);
    shortx8 b0v = bp8[0];
    shortx8 b1v = bp8[1];

    __syncthreads();
    *reinterpret_cast<shortx8*>(aw)     = w0;
    *reinterpret_cast<shortx8*>(aw + 8) = w1;
    *reinterpret_cast<shortx8*>(bw)     = b0v;
    *reinterpret_cast<shortx8*>(bw + 8) = b1v;
    __syncthreads();

#pragma unroll
    for (int kt = 0; kt < 2; ++kt) {
      shortx8 a0 = *reinterpret_cast<const shortx8*>(&As[(wr*32      + lr) * 72 + kt*32 + lg*8]);
      shortx8 a1 = *reinterpret_cast<const shortx8*>(&As[(wr*32 + 16 + lr) * 72 + kt*32 + lg*8]);
      shortx8 bb0 = *reinterpret_cast<const shortx8*>(&Bs[(wc*32      + lr) * 72 + kt*32 + lg*8]);
      shortx8 bb1 = *reinterpret_cast<const shortx8*>(&Bs[(wc*32 + 16 + lr) * 72 + kt*32 + lg*8]);
      acc00 = __builtin_amdgcn_mfma_f32_16x16x32_bf16(a0, bb0, acc00, 0, 0, 0);
      acc01 = __builtin_amdgcn_mfma_f32_16x16x32_bf16(a0, bb1, acc01, 0, 0, 0);
      acc10 = __builtin_amdgcn_mfma_f32_16x16x32_bf16(a1, bb0, acc10, 0, 0, 0);
      acc11 = __builtin_amdgcn_mfma_f32_16x16x32_bf16(a1, bb1, acc11, 0, 0, 0);
    }
  }

  const int colA = col0 + wc * 32 + lr;
  const int colB = colA + 16;
  const bool okA = colA < Nn, okB = colB < Nn;
  const float biasA = (bp && okA) ? bp[colA] : 0.f;
  const float biasB = (bp && okB) ? bp[colB] : 0.f;
  const int rb0 = row0 + wr * 32 + lg * 4;
  const int rb1 = rb0 + 16;
#pragma unroll
  for (int jj = 0; jj < 4; ++jj) {
    int ra = rb0 + jj, rb = rb1 + jj;
    float v00 = acc00[jj] + biasA, v01 = acc01[jj] + biasB;
    float v10 = acc10[jj] + biasA, v11 = acc11[jj] + biasB;
    if (ra < M) {
      if (co) { if (okA) co[(long long)ra * ldc + colA] = v00;
                if (okB) co[(long long)ra * ldc + colB] = v01; }
      if (cb) { if (okA) cb[(long long)ra * ldc + colA] = f2bf(v00);
                if (okB) cb[(long long)ra * ldc + colB] = f2bf(v01); }
    }
    if (rb < M) {
      if (co) { if (okA) co[(long long)rb * ldc + colA] = v10;
                if (okB) co[(long long)rb * ldc + colB] = v11; }
      if (cb) { if (okA) cb[(long long)rb * ldc + colA] = f2bf(v10);
                if (okB) cb[(long long)rb * ldc + colB] = f2bf(v11); }
    }
  }
}

// ---------------- z-batched 64² GEMM ----------------
__global__ __launch_bounds__(256)
void gemm_mfma(const void* __restrict__ Ain, const unsigned short* __restrict__ Bt,
               const float* __restrict__ bias, float* __restrict__ Co,
               unsigned short* __restrict__ Cb,
               int M, int Nn, int K, int lda, int ldb, int ldc, int abf,
               long long sA, long long sB, long long sBias, long long sC)
{
  const int z = blockIdx.z;
  const void* A = abf ? (const void*)((const unsigned short*)Ain + z * sA)
                      : (const void*)((const float*)Ain + z * sA);
  gemm64_body(A, Bt + z * sB, bias ? bias + z * sBias : nullptr,
              Co ? Co + z * sC : nullptr, Cb ? Cb + z * sC : nullptr,
              M, Nn, K, lda, ldb, ldc, abf, blockIdx.x, blockIdx.y);
}

// ---------------- multi-job 64² GEMM ----------------
struct GJob {
  const void* A; const unsigned short* B; const float* bias;
  float* Co; unsigned short* Cb;
  int M, Nn, K, lda, ldb, ldc, abf, tx;
};
struct GJobs { GJob j[3]; int ends[3]; int n; };

__global__ __launch_bounds__(256)
void gemm_jobs(GJobs js)
{
  const int bid = blockIdx.x;
#pragma unroll
  for (int q = 0; q < 3; ++q) {
    if (q < js.n && bid < js.ends[q]) {
      int start = q ? js.ends[q - 1] : 0;
      int local = bid - start;
      const GJob& J = js.j[q];
      gemm64_body(J.A, J.B, J.bias, J.Co, J.Cb,
                  J.M, J.Nn, J.K, J.lda, J.ldb, J.ldc, J.abf,
                  local % J.tx, local / J.tx);
      return;
    }
  }
}

// ------- 128²-tile GEMM body, global_load_lds staging; optional BN-stat partials -------
__device__ __forceinline__
void g128_body(const unsigned short* __restrict__ Ab, const unsigned short* __restrict__ Bt,
               const float* __restrict__ bp, float* __restrict__ co,
               unsigned short* __restrict__ cb, float* __restrict__ psb, float* __restrict__ pqb,
               int M, int Nn, int K, int lda, int ldb, int ldc, int bx, int by)
{
  __shared__ unsigned short As[128 * 64];
  __shared__ unsigned short Bs[128 * 64];

  const int tid = threadIdx.x;
  const int row0 = bx * 128, col0 = by * 128;
  const int wid = tid >> 6, lane = tid & 63;
  const int wr = wid >> 1, wc = wid & 1;
  const int lr = lane & 15, lg = lane >> 4;

  floatx4 acc[4][4];
#pragma unroll
  for (int mf = 0; mf < 4; ++mf)
#pragma unroll
    for (int nf = 0; nf < 4; ++nf) acc[mf][nf] = floatx4{0.f,0.f,0.f,0.f};

  const int rsub = tid >> 3;
  const int csub = (tid & 7) * 8;

  for (int k0 = 0; k0 < K; k0 += 64) {
    __syncthreads();
#pragma unroll
    for (int it = 0; it < 4; ++it) {
      int r = it * 32 + rsub;
      gload16(Ab + (long long)(row0 + r) * lda + k0 + csub, As + it * 2048 + tid * 8);
      gload16(Bt + (long long)(col0 + r) * ldb + k0 + csub, Bs + it * 2048 + tid * 8);
    }
    __syncthreads();

#pragma unroll
    for (int kt = 0; kt < 2; ++kt) {
      shortx8 af[4], bf[4];
#pragma unroll
      for (int mf = 0; mf < 4; ++mf)
        af[mf] = *reinterpret_cast<const shortx8*>(&As[(wr*64 + mf*16 + lr) * 64 + kt*32 + lg*8]);
#pragma unroll
      for (int nf = 0; nf < 4; ++nf)
        bf[nf] = *reinterpret_cast<const shortx8*>(&Bs[(wc*64 + nf*16 + lr) * 64 + kt*32 + lg*8]);
#pragma unroll
      for (int mf = 0; mf < 4; ++mf)
#pragma unroll
        for (int nf = 0; nf < 4; ++nf)
          acc[mf][nf] = __builtin_amdgcn_mfma_f32_16x16x32_bf16(af[mf], bf[nf], acc[mf][nf], 0, 0, 0);
    }
  }

#pragma unroll
  for (int nf = 0; nf < 4; ++nf) {
    const int col = col0 + wc * 64 + nf * 16 + lr;
    if (col >= Nn) continue;
    const float bv = bp ? bp[col] : 0.f;
#pragma unroll
    for (int mf = 0; mf < 4; ++mf) {
      const int rbase = row0 + wr * 64 + mf * 16 + lg * 4;
#pragma unroll
      for (int jj = 0; jj < 4; ++jj) {
        int row = rbase + jj;
        if (row >= M) continue;
        float v = acc[mf][nf][jj] + bv;
        if (co) co[(long long)row * ldc + col] = v;
        if (cb) cb[(long long)row * ldc + col] = f2bf(v);
      }
    }
  }

  if (psb) {
    __syncthreads();
    float* sb = (float*)As;
    sb[tid] = 0.f;
    __syncthreads();
#pragma unroll
    for (int nf = 0; nf < 4; ++nf) {
      const int lcol = wc * 64 + nf * 16 + lr;
      const int col = col0 + lcol;
      float s = 0.f, q = 0.f;
      if (col < Nn) {
        const float bv = bp ? bp[col] : 0.f;
#pragma unroll
        for (int mf = 0; mf < 4; ++mf) {
          const int rbase = row0 + wr * 64 + mf * 16 + lg * 4;
#pragma unroll
          for (int jj = 0; jj < 4; ++jj) {
            if (rbase + jj < M) { float v = acc[mf][nf][jj] + bv; s += v; q += v * v; }
          }
        }
      }
      atomicAdd(&sb[lcol], s);
      atomicAdd(&sb[128 + lcol], q);
    }
    __syncthreads();
    if (tid < 128) {
      psb[col0 + tid] = sb[tid];
      pqb[col0 + tid] = sb[128 + tid];
    }
  }
}

__global__ __launch_bounds__(256)
void gemm128g(const unsigned short* __restrict__ Ab, const unsigned short* __restrict__ Bt,
              const float* __restrict__ bias, float* __restrict__ Co,
              unsigned short* __restrict__ Cb, float* __restrict__ ps, float* __restrict__ pq,
              int M, int Nn, int K, int lda, int ldb, int ldc,
              long long sA, long long sB, long long sBias, long long sC)
{
  const int z = blockIdx.z;
  long long so = ((long long)blockIdx.x * gridDim.z + z) * ldc;
  g128_body(Ab + z * sA, Bt + z * sB, bias ? bias + z * sBias : nullptr,
            Co ? Co + z * sC : nullptr, Cb ? Cb + z * sC : nullptr,
            ps ? ps + so : nullptr, pq ? pq + so : nullptr,
            M, Nn, K, lda, ldb, ldc, blockIdx.x, blockIdx.y);
}

// ------- f_u = relu(norm(h)) -> bf16, f_v = mean_d f_u (4-slice stats fold) -------
__global__ __launch_bounds__(256)
void fu_fv(const float* __restrict__ h, const float* __restrict__ ps,
           const float* __restrict__ pq, unsigned short* __restrict__ fub,
           float* __restrict__ fv)
{
  const int bid = blockIdx.x;
  const int b = bid / N, n = bid % N;
  const int c = blockIdx.y * 256 + threadIdx.x;
  const int idx = n * C + c;
  float s = 0.f, q = 0.f;
#pragma unroll
  for (int sl = 0; sl < 4; ++sl) { s += ps[sl * (N * C) + idx]; q += pq[sl * (N * C) + idx]; }
  float m = s / (float)M_BD;
  float rv = rsqrtf(q / (float)M_BD - m * m + BN_EPS);
  float acc = 0.f;
  for (int d = 0; d < D; ++d) {
    float v = h[((long long)n * M_BD + b * D + d) * C + c];
    v = fmaxf((v - m) * rv, 0.f);
    fub[((long long)bid * D + d) * C + c] = f2bf(v);
    acc += v;
  }
  fv[(long long)bid * C + c] = acc * (1.0f / (float)D);
}

// -- fused: fam softmax (0..18) + vx transpose (19..82) + cosine mask (83..90) --
__global__ __launch_bounds__(256)
void softvxt_k(const float* __restrict__ Sf, unsigned short* __restrict__ Ppb,
               const unsigned short* __restrict__ kvx, unsigned short* __restrict__ vxtb,
               const float* __restrict__ fv, float* __restrict__ maskp)
{
  const int tid = threadIdx.x;
  if (blockIdx.x < 19) {
    int row = blockIdx.x * 256 + tid;
    if (row >= M_BND) return;
    const float* p = Sf + (long long)row * 49;
    float v[49];
    float m = -1e30f;
#pragma unroll
    for (int j = 0; j < 49; ++j) { v[j] = p[j] * ATT_SCALE; m = fmaxf(m, v[j]); }
    float s = 0.f;
#pragma unroll
    for (int j = 0; j < 49; ++j) { v[j] = __expf(v[j] - m); s += v[j]; }
    float inv = 1.f / s;
    unsigned short* o = Ppb + (long long)row * 64;
#pragma unroll
    for (int j = 0; j < 49; ++j) o[j] = f2bf(v[j] * inv);
#pragma unroll
    for (int j = 49; j < 64; ++j) o[j] = 0;
    return;
  }
  if (blockIdx.x < 83) {
    const int i = blockIdx.x - 19;
    const int b = i >> 3, cc = i & 7;
    __shared__ unsigned short t[49][65];
    for (int idx = tid; idx < 49 * 64; idx += 256) {
      int rr = idx >> 6, k = idx & 63;
      t[rr][k] = kvx[(long long)(b * 49 + rr) * 768 + 256 + cc * 64 + k];
    }
    __syncthreads();
    for (int idx = tid; idx < 64 * 64; idx += 256) {
      int n = idx >> 6, kk = idx & 63;
      vxtb[((long long)b * 512 + cc * 64 + n) * 64 + kk] = (kk < 49) ? t[kk][n] : (unsigned short)0;
    }
    return;
  }
  const int b = blockIdx.x - 83;
  __shared__ float fl[N][C];
  __shared__ float adj[N][N];
  __shared__ float nrm[N];
  __shared__ float dis[N];
  for (int idx = tid; idx < N * C; idx += 256)
    fl[idx / C][idx % C] = fv[(long long)b * N * C + idx];
  __syncthreads();
  if (tid < N * N) {
    int i = tid / N, j = tid % N;
    float s = 0.f;
    for (int k = 0; k < C; ++k) s += fl[i][k] * fl[j][k];
    adj[i][j] = s;
  }
  __syncthreads();
  if (tid < N) nrm[tid] = fmaxf(sqrtf(adj[tid][tid]), 1e-12f);
  __syncthreads();
  if (tid < N * N) {
    int i = tid / N, j = tid % N;
    adj[i][j] = adj[i][j] / (nrm[i] * nrm[j]);
  }
  __syncthreads();
  if (tid < N) {
    float s = 0.f;
    for (int j = 0; j < N; ++j) s += adj[tid][j];
    dis[tid] = rsqrtf(s);
  }
  __syncthreads();
  if (tid < N * N) {
    int i = tid / N, j = tid % N;
    maskp[b * E + tid] = adj[i][j] * dis[i] * dis[j];
  }
}

// ------- edge finish: inline QK^T (MFMA) + softmax + colsum@V + st2 = <A^T A, G> -------
__global__ __launch_bounds__(256)
void edge_finish(const unsigned short* __restrict__ qkvfe, const float* __restrict__ G,
                 float* __restrict__ S1, float* __restrict__ eS)
{
  const int bid = blockIdx.x;           // b*E + e
  const int b = bid / E, e = bid % E;
  const int i = e / N, j = e % N;
  const unsigned short* Qp = qkvfe + (long long)(b * N + j) * D * 1024;        // qf rows
  const unsigned short* Kp = qkvfe + (long long)(b * N + i) * D * 1024 + 256;  // kf rows
  const unsigned short* Vp = qkvfe + (long long)(b * N + i) * D * 1024 + 512;
  const float* Gp = G + (long long)(b * N + i) * 2401;

  // 32KB overlay: phase A = swizzled q/k stage [64][128] each; phase B = aT/g/abT
  __shared__ char smem_raw[33024] __attribute__((aligned(16)));
  unsigned short* sq = (unsigned short*)smem_raw;           // 64*128 = 16KB
  unsigned short* sk = sq + 64 * 128;                        // 16KB
  float (*aT)[53] = (float (*)[53])smem_raw;                 // 49x53 f32
  float (*g)[53]  = (float (*)[53])(smem_raw + 10400);
  unsigned short (*abT)[72] = (unsigned short (*)[72])(smem_raw + 20800);
  __shared__ float ws[52];
  __shared__ float r0[4], r1[4];

  const int tid = threadIdx.x;
  const int wid = tid >> 6, lane = tid & 63;
  const int lr = lane & 15, lg = lane >> 4;

  // ---- QK^T: Ct[dj][di] = k_dj . q_di  (K@Q^T), K=256 in 2 halves of 128 ----
  floatx4 qk[4];
#pragma unroll
  for (int f = 0; f < 4; ++f) qk[f] = floatx4{0.f,0.f,0.f,0.f};
  for (int p = 0; p < 2; ++p) {
    __syncthreads();
    for (int idx = tid; idx < 49 * 16; idx += 256) {
      int row = idx >> 4, seg = idx & 15;
      int dsti = row * 128 + ((seg ^ (row & 7)) << 3);
      *reinterpret_cast<shortx8*>(sq + dsti) =
          *reinterpret_cast<const shortx8*>(Qp + row * 1024 + p * 128 + seg * 8);
      *reinterpret_cast<shortx8*>(sk + dsti) =
          *reinterpret_cast<const shortx8*>(Kp + row * 1024 + p * 128 + seg * 8);
    }
    __syncthreads();
#pragma unroll
    for (int kt = 0; kt < 4; ++kt) {
      const int arow = wid * 16 + lr;
      shortx8 a = *reinterpret_cast<const shortx8*>(
          sk + arow * 128 + (((kt * 4 + lg) ^ (arow & 7)) << 3));
#pragma unroll
      for (int f = 0; f < 4; ++f) {
        const int brow = f * 16 + lr;
        shortx8 bb = *reinterpret_cast<const shortx8*>(
            sq + brow * 128 + (((kt * 4 + lg) ^ (brow & 7)) << 3));
        qk[f] = __builtin_amdgcn_mfma_f32_16x16x32_bf16(a, bb, qk[f], 0, 0, 0);
      }
    }
  }
  __syncthreads();   // stage dead; overlay aT/g/abT

  // write scores into aT[dj][di]; load g
#pragma unroll
  for (int f = 0; f < 4; ++f) {
#pragma unroll
    for (int jj = 0; jj < 4; ++jj) {
      int dj = wid * 16 + lg * 4 + jj;
      int di = f * 16 + lr;
      if (dj < D && di < D) aT[dj][di] = qk[f][jj] * ATT_SCALE;
    }
  }
  for (int idx = tid; idx < 49 * 49; idx += 256) {
    int di = idx / 49, dj = idx - di * 49;
    g[di][dj] = Gp[idx];
  }
  __syncthreads();
  // softmax over dj for each di (column di of aT)
  if (tid < D) {
    float m = -1e30f;
    for (int jj = 0; jj < D; ++jj) m = fmaxf(m, aT[jj][tid]);
    float s = 0.f;
    for (int jj = 0; jj < D; ++jj) { float ev = __expf(aT[jj][tid] - m); aT[jj][tid] = ev; s += ev; }
    float inv = 1.f / s;
    for (int jj = 0; jj < D; ++jj) aT[jj][tid] *= inv;
  }
  __syncthreads();
  for (int idx = tid; idx < 64 * 64; idx += 256) {
    int dj = idx >> 6, di = idx & 63;
    float v = (dj < D && di < D) ? aT[dj][di] : 0.f;
    abT[dj][di] = f2bf(v);
  }
  if (tid < D) {
    float s = 0.f;
    for (int di = 0; di < D; ++di) s += aT[tid][di];
    ws[tid] = s;
  }
  __syncthreads();

  // st2 = <A^T A, G> via MFMA on abT
  floatx4 acc[4];
#pragma unroll
  for (int tk = 0; tk < 4; ++tk) acc[tk] = floatx4{0.f,0.f,0.f,0.f};
  shortx8 af0 = *reinterpret_cast<const shortx8*>(&abT[wid * 16 + lr][lg * 8]);
  shortx8 af1 = *reinterpret_cast<const shortx8*>(&abT[wid * 16 + lr][32 + lg * 8]);
#pragma unroll
  for (int tk = 0; tk < 4; ++tk) {
    shortx8 bf0v = *reinterpret_cast<const shortx8*>(&abT[tk * 16 + lr][lg * 8]);
    shortx8 bf1v = *reinterpret_cast<const shortx8*>(&abT[tk * 16 + lr][32 + lg * 8]);
    acc[tk] = __builtin_amdgcn_mfma_f32_16x16x32_bf16(af0, bf0v, acc[tk], 0, 0, 0);
    acc[tk] = __builtin_amdgcn_mfma_f32_16x16x32_bf16(af1, bf1v, acc[tk], 0, 0, 0);
  }
  float st2 = 0.f;
#pragma unroll
  for (int tk = 0; tk < 4; ++tk) {
    int kcol = tk * 16 + lr;
#pragma unroll
    for (int rg = 0; rg < 4; ++rg) {
      int jrow = wid * 16 + lg * 4 + rg;
      if (jrow < D && kcol < D) st2 = fmaf(acc[tk][rg], g[jrow][kcol], st2);
    }
  }

  // S1 = colsum(A) @ V  — 2 bf16 per lane per row
  const unsigned* Vp32 = reinterpret_cast<const unsigned*>(Vp);
  float s1a = 0.f, s1b = 0.f;
  for (int dk = 0; dk < D; ++dk) {
    unsigned u = Vp32[dk * 512 + tid];
    float w = ws[dk];
    s1a = fmaf(w, bf2f((unsigned short)(u & 0xffffu)), s1a);
    s1b = fmaf(w, bf2f((unsigned short)(u >> 16)), s1b);
  }
  S1[(long long)bid * C + 2 * tid]     = s1a;
  S1[(long long)bid * C + 2 * tid + 1] = s1b;
  float st = s1a + s1b;

  for (int off = 32; off; off >>= 1) { st += __shfl_down(st, off); st2 += __shfl_down(st2, off); }
  if (lane == 0) { r0[wid] = st; r1[wid] = st2; }
  __syncthreads();
  if (tid == 0) {
    eS[bid * 2 + 0] = r0[0] + r0[1] + r0[2] + r0[3];
    eS[bid * 2 + 1] = r1[0] + r1[1] + r1[2] + r1[3];
  }
}

// ---------------- f_e = (S1/D - me)*rve * mask (me/rve computed inline) ----------------
__global__ __launch_bounds__(256)
void fe_k(const float* __restrict__ S1, const float* __restrict__ eS,
          const float* __restrict__ maskp, float* __restrict__ fe)
{
  __shared__ float csh[3];
  long long idx0 = (long long)blockIdx.x * 256;
  long long be = idx0 / C;
  int e = (int)(be % E);
  if (threadIdx.x == 0) {
    float s = 0.f, q = 0.f;
    for (int b = 0; b < B; ++b) { s += eS[(b * E + e) * 2]; q += eS[(b * E + e) * 2 + 1]; }
    const float inv = 1.f / (float)(B * D * C);
    float m = s * inv;
    csh[0] = m;
    csh[1] = rsqrtf(q * inv - m * m + BN_EPS);
    csh[2] = maskp[be];
  }
  __syncthreads();
  long long idx = idx0 + threadIdx.x;
  fe[idx] = (S1[idx] * (1.0f / (float)D) - csh[0]) * csh[1] * csh[2];
}

// ---------------- GNN: BN stats per e over agg = A[i]+B[j]+EW[e] ----------------
__global__ __launch_bounds__(256)
void agg_stats(const float* __restrict__ ABUV, const float* __restrict__ EW,
               float* __restrict__ mu_e, float* __restrict__ rs_e)
{
  const int e = blockIdx.x;
  const int i = e / N, j = e % N;
  const int tid = threadIdx.x;
  float s = 0.f, q = 0.f;
  for (int idx = tid; idx < B * C; idx += 256) {
    int b = idx >> 9, c = idx & 511;
    float v = ABUV[(long long)(b * N + i) * 2048 + c]
            + ABUV[(long long)(b * N + j) * 2048 + 512 + c]
            + EW[((long long)b * E + e) * C + c];
    s += v; q += v * v;
  }
  for (int off = 32; off; off >>= 1) { s += __shfl_down(s, off); q += __shfl_down(q, off); }
  __shared__ float r0[4], r1[4];
  int wid = tid >> 6, lane = tid & 63;
  if (lane == 0) { r0[wid] = s; r1[wid] = q; }
  __syncthreads();
  if (tid == 0) {
    float ss = r0[0] + r0[1] + r0[2] + r0[3];
    float qq = r1[0] + r1[1] + r1[2] + r1[3];
    float m = ss / (float)(B * C);
    mu_e[e] = m;
    rs_e[e] = rsqrtf(qq / (float)(B * C) - m * m + BN_EPS);
  }
}

// -- fused: ed update + msg + pre + node-BN partials; grid (B*N, 2), one c per thread --
__global__ __launch_bounds__(256)
void edmsg_k(float* __restrict__ fe, const float* __restrict__ ABUV,
             const float* __restrict__ EW, const float* __restrict__ mu_e,
             const float* __restrict__ rs_e, float* __restrict__ pre,
             float* __restrict__ nps, float* __restrict__ npq)
{
  const int bid = blockIdx.x;
  const int b = bid / N, i = bid % N;
  const int half = blockIdx.y;
  const int tid = threadIdx.x;
  const int c = half * 256 + tid;

  float ai = ABUV[(long long)(b * N + i) * 2048 + c];
  float sv[N];
  float m = -1e30f;
#pragma unroll
  for (int jn = 0; jn < N; ++jn) {
    int e = i * N + jn;
    float v = ai + ABUV[(long long)(b * N + jn) * 2048 + 512 + c]
            + EW[((long long)b * E + e) * C + c];
    v = (v - mu_e[e]) * rs_e[e];
    float ed = fe[((long long)b * E + e) * C + c] + fmaxf(v, 0.f);
    fe[((long long)b * E + e) * C + c] = ed;
    float sg = 1.f / (1.f + __expf(-ed));
    sv[jn] = sg; m = fmaxf(m, sg);
  }
  float sum = 0.f;
#pragma unroll
  for (int jn = 0; jn < N; ++jn) { float ev = __expf(sv[jn] - m); sv[jn] = ev; sum += ev; }
  float acc = 0.f;
#pragma unroll
  for (int jn = 0; jn < N; ++jn)
    acc = fmaf(sv[jn], ABUV[(long long)(b * N + jn) * 2048 + 1536 + c], acc);
  acc /= (sum * (float)N);
  float pv = ABUV[(long long)bid * 2048 + 1024 + c] + acc;
  pre[(long long)bid * C + c] = pv;
  float ls = pv, lq = pv * pv;
  for (int off = 32; off; off >>= 1) { ls += __shfl_down(ls, off); lq += __shfl_down(lq, off); }
  __shared__ float r0[4], r1[4];
  int wid = tid >> 6, lane = tid & 63;
  if (lane == 0) { r0[wid] = ls; r1[wid] = lq; }
  __syncthreads();
  if (tid == 0) {
    nps[(i * B + b) * 2 + half] = r0[0] + r0[1] + r0[2] + r0[3];
    npq[(i * B + b) * 2 + half] = r1[0] + r1[1] + r1[2] + r1[3];
  }
}

__global__ void xv_update(float* __restrict__ xv, const float* __restrict__ pre,
                          const float* __restrict__ nps, const float* __restrict__ npq)
{
  long long idx = (long long)blockIdx.x * 256 + threadIdx.x;
  if (idx >= (long long)B * N * C) return;
  int i = (int)((idx / C) % N);
  float s = 0.f, q = 0.f;
#pragma unroll
  for (int t = 0; t < B * 2; ++t) { s += nps[i * B * 2 + t]; q += npq[i * B * 2 + t]; }
  float mu = s * (1.f / (float)(B * C));
  float rs = rsqrtf(q * (1.f / (float)(B * C)) - mu * mu + BN_EPS);
  float v = xv[idx] + (pre[idx] - mu) * rs;
  xv[idx] = fmaxf(v, 0.f);
}

// ------- outputs (final xv_update folded into cl part) -------
__global__ __launch_bounds__(256)
void out_k(const float* __restrict__ xv, const float* __restrict__ pre,
           const float* __restrict__ nps, const float* __restrict__ npq,
           const float* __restrict__ sc,
           const float* __restrict__ ed, const float* __restrict__ w,
           const float* __restrict__ bias, float* __restrict__ out)
{
  const int bid = blockIdx.x;
  const int tid = threadIdx.x;
  int wid = tid >> 6, lane = tid & 63;
  if (bid < B * N) {
    const int b = bid / N, i = bid % N;
    float s = 0.f, q = 0.f;
#pragma unroll
    for (int t = 0; t < B * 2; ++t) { s += nps[i * B * 2 + t]; q += npq[i * B * 2 + t]; }
    float mu = s * (1.f / (float)(B * C));
    float rs = rsqrtf(q * (1.f / (float)(B * C)) - mu * mu + BN_EPS);
    float sxx = 0.f, sss = 0.f, sxs = 0.f;
    for (int c = tid; c < C; c += 256) {
      float xvv = fmaxf(xv[(long long)bid * C + c] + (pre[(long long)bid * C + c] - mu) * rs, 0.f);
      float scv = fmaxf(sc[i * C + c], 0.f);
      sxx += xvv * xvv; sss += scv * scv; sxs += xvv * scv;
    }
    for (int off = 32; off; off >>= 1) {
      sxx += __shfl_down(sxx, off);
      sss += __shfl_down(sss, off);
      sxs += __shfl_down(sxs, off);
    }
    __shared__ float r0[4], r1[4], r2[4];
    if (lane == 0) { r0[wid] = sxx; r1[wid] = sss; r2[wid] = sxs; }
    __syncthreads();
    if (tid == 0) {
      float a = r0[0] + r0[1] + r0[2] + r0[3];
      float ss = r1[0] + r1[1] + r1[2] + r1[3];
      float p = r2[0] + r2[1] + r2[2] + r2[3];
      float nx = fmaxf(sqrtf(a), 1e-12f);
      float ns = fmaxf(sqrtf(ss), 1e-12f);
      out[b * N + i] = p / (nx * ns);
    }
  } else {
    const int eb = bid - B * N;
    float a0 = 0, a1 = 0, a2 = 0, a3 = 0;
    for (int c = tid; c < C; c += 256) {
      float v = ed[(long long)eb * C + c];
      a0 = fmaf(v, w[c * 4 + 0], a0);
      a1 = fmaf(v, w[c * 4 + 1], a1);
      a2 = fmaf(v, w[c * 4 + 2], a2);
      a3 = fmaf(v, w[c * 4 + 3], a3);
    }
    for (int off = 32; off; off >>= 1) {
      a0 += __shfl_down(a0, off);
      a1 += __shfl_down(a1, off);
      a2 += __shfl_down(a2, off);
      a3 += __shfl_down(a3, off);
    }
    __shared__ float r[4][4];
    if (lane == 0) { r[wid][0] = a0; r[wid][1] = a1; r[wid][2] = a2; r[wid][3] = a3; }
    __syncthreads();
    if (tid < 4) {
      float sr = r[0][tid] + r[1][tid] + r[2][tid] + r[3][tid];
      out[B * N + eb * 4 + tid] = sr + bias[tid];
    }
  }
}

} // namespace

extern "C" void kernel_launch(void* const* d_in, const int* in_sizes, int n_in,
                              void* d_out, int out_size, void* d_ws, size_t ws_size,
                              hipStream_t stream)
{
  (void)in_sizes; (void)n_in; (void)out_size; (void)ws_size;
  const float* x      = (const float*)d_in[0];
  const float* Wc     = (const float*)d_in[1];
  const float* bc     = (const float*)d_in[2];
  const float* fam_wq = (const float*)d_in[3];
  const float* fam_bq = (const float*)d_in[4];
  const float* fam_wk = (const float*)d_in[5];
  const float* fam_bk = (const float*)d_in[6];
  const float* fam_wv = (const float*)d_in[7];
  const float* fam_bv = (const float*)d_in[8];
  const float* arm_wq = (const float*)d_in[9];
  const float* arm_bq = (const float*)d_in[10];
  const float* arm_wk = (const float*)d_in[11];
  const float* arm_bk = (const float*)d_in[12];
  const float* arm_wv = (const float*)d_in[13];
  const float* arm_bv = (const float*)d_in[14];
  const float* ep_w   = (const float*)d_in[15];
  const float* ep_b   = (const float*)d_in[16];
  const float* gw[10] = {
    (const float*)d_in[17], (const float*)d_in[18], (const float*)d_in[19],
    (const float*)d_in[20], (const float*)d_in[21],
    (const float*)d_in[22], (const float*)d_in[23], (const float*)d_in[24],
    (const float*)d_in[25], (const float*)d_in[26]};
  const float* sc     = (const float*)d_in[27];
  const float* efc_w  = (const float*)d_in[28];
  const float* efc_b  = (const float*)d_in[29];
  float* out = (float*)d_out;

  char* wsb = (char*)d_ws;
  size_t off = 0;
  auto allocf = [&](size_t n) { float* p = (float*)(wsb + off); off += ((n * 4 + 255) / 256) * 256; return p; };
  auto allocu = [&](size_t n) { unsigned short* p = (unsigned short*)(wsb + off); off += ((n * 2 + 255) / 256) * 256; return p; };

  float* h_t   = allocf(2408448);
  float* bnp_s = allocf(24576);            // 4 slices x N x C
  float* bnp_q = allocf(24576);
  float* f_v   = allocf(49152);
  float* Sf    = allocf(230496);           // 8*588*49
  float* Gm    = allocf(230496);           // 96*49*49
  float* S1    = allocf(589824);
  float* fe    = allocf(589824);
  float* EW    = allocf(589824);
  float* eS    = allocf(2304);
  float* mask  = allocf(1152);
  float* ABUV  = allocf(196608);
  float* pre   = allocf(49152);
  float* mu_e  = allocf(144);
  float* rs_e  = allocf(144);
  float* nps   = allocf(192);
  float* npq   = allocf(192);
  float* kvbias  = allocf(768);
  float* qkvbias = allocf(1024);           // [arm_bq|arm_bk|b2]

  unsigned short* Wct    = allocu(3145728);
  unsigned short* famqt  = allocu(131072);
  unsigned short* kvwt   = allocu(393216);   // [768][512]: fam_wk | fam_wv
  unsigned short* qkw2t  = allocu(524288);   // [1024][512]: arm_wq | arm_wk | W2^T
  unsigned short* epwt   = allocu(262144);
  unsigned short* armwvb = allocu(262144);   // arm_wv row-major bf16
  unsigned short* wet0   = allocu(262144);
  unsigned short* wet1   = allocu(262144);
  unsigned short* ABUVt0 = allocu(1048576);
  unsigned short* ABUVt1 = allocu(1048576);
  unsigned short* xb     = allocu(262144);   // [512][512] (rows padded for gload)
  unsigned short* fub    = allocu(2408448);
  unsigned short* q1b    = allocu(1204224);  // [4704][256]
  unsigned short* kxvx_b = allocu(350208);   // [456][768] (pad rows for B overread)
  unsigned short* Ppb    = allocu(301056);   // [4704][64]
  unsigned short* vxtb   = allocu(262144);   // [8][512][64]
  unsigned short* featb  = allocu(2424832);  // [4736][512] (rows padded for gload)
  unsigned short* qkvfe  = allocu(4915200);  // [4800][1024]: q|k|vfe (pad rows)

  dim3 blk(256);

  // -------- weight transpose+cast (28 jobs) + castrow/bias/b2 branch (z=28) --------
  TCJobs tj{};
  int jn = 0;
  for (int n = 0; n < 12; ++n) { tj.src[jn] = Wc + (size_t)n * C * C; tj.dst[jn] = Wct + (size_t)n * C * C; tj.nn[jn] = C; ++jn; }
  tj.src[jn] = fam_wq; tj.dst[jn] = famqt;             tj.nn[jn] = H; ++jn;
  tj.src[jn] = fam_wk; tj.dst[jn] = kvwt;              tj.nn[jn] = H; ++jn;
  tj.src[jn] = fam_wv; tj.dst[jn] = kvwt + 256 * 512;  tj.nn[jn] = C; ++jn;
  tj.src[jn] = arm_wq; tj.dst[jn] = qkw2t;             tj.nn[jn] = H; ++jn;
  tj.src[jn] = arm_wk; tj.dst[jn] = qkw2t + 256 * 512; tj.nn[jn] = H; ++jn;
  tj.src[jn] = ep_w;   tj.dst[jn] = epwt;              tj.nn[jn] = C; ++jn;
  tj.src[jn] = gw[2];  tj.dst[jn] = wet0;              tj.nn[jn] = C; ++jn;
  tj.src[jn] = gw[7];  tj.dst[jn] = wet1;              tj.nn[jn] = C; ++jn;
  tj.src[jn] = gw[0];  tj.dst[jn] = ABUVt0;               tj.nn[jn] = C; ++jn;
  tj.src[jn] = gw[1];  tj.dst[jn] = ABUVt0 + 1 * C * C;   tj.nn[jn] = C; ++jn;
  tj.src[jn] = gw[3];  tj.dst[jn] = ABUVt0 + 2 * C * C;   tj.nn[jn] = C; ++jn;
  tj.src[jn] = gw[4];  tj.dst[jn] = ABUVt0 + 3 * C * C;   tj.nn[jn] = C; ++jn;
  tj.src[jn] = gw[5];  tj.dst[jn] = ABUVt1;               tj.nn[jn] = C; ++jn;
  tj.src[jn] = gw[6];  tj.dst[jn] = ABUVt1 + 1 * C * C;   tj.nn[jn] = C; ++jn;
  tj.src[jn] = gw[8];  tj.dst[jn] = ABUVt1 + 2 * C * C;   tj.nn[jn] = C; ++jn;
  tj.src[jn] = gw[9];  tj.dst[jn] = ABUVt1 + 3 * C * C;   tj.nn[jn] = C; ++jn;
  tcast_k<<<dim3(16, 16, 29), blk, 0, stream>>>(tj, x, xb, arm_wv, armwvb,
      fam_bk, fam_bv, arm_bq, arm_bk, arm_bv, ep_w, ep_b, kvbias, qkvbias);

  // h[n] = x @ Wc[n] + bc[n]  (128² gload tiles, BN stats fused)
  gemm128g<<<dim3(4, 4, 12), blk, 0, stream>>>(xb, Wct, bc, h_t, nullptr, bnp_s, bnp_q,
      M_BD, C, C, C, C, C, 0LL, (long long)C * C, (long long)C, (long long)M_BD * C);
  fu_fv<<<dim3(B * N, 2), blk, 0, stream>>>(h_t, bnp_s, bnp_q, fub, f_v);

  // batched: q1 (fam q), kxvx (fam k|v), W2^T = ep_w^T @ arm_wv^T
  {
    GJobs js{};
    js.j[0] = {fub,  famqt,  fam_bq, nullptr, q1b,            M_BND, H,   C, C, C, H,   1, 74};
    js.j[1] = {xb,   kvwt,   kvbias, nullptr, kxvx_b,         M_BD,  768, C, C, C, 768, 1, 7};
    js.j[2] = {epwt, armwvb, nullptr, nullptr, qkw2t + 512 * 512, C,  C,   C, C, C, C,   1, 8};
    js.ends[0] = 296; js.ends[1] = 380; js.ends[2] = 444; js.n = 3;
    gemm_jobs<<<dim3(444), blk, 0, stream>>>(js);
  }
  // Sf[b] = q1[b] @ kx[b]^T  (588 x 49)
  gemm_mfma<<<dim3(10, 1, 8), blk, 0, stream>>>(q1b, kxvx_b, nullptr, Sf, nullptr,
      588, 49, H, H, 768, 49, 1, 588LL * 256, 49LL * 768, 0LL, 588LL * 49);
  softvxt_k<<<dim3(91), blk, 0, stream>>>(Sf, Ppb, kxvx_b, vxtb, f_v, mask);
  // feat[b] = P[b] @ vx[b]  (588 x 512, K=64)
  gemm_mfma<<<dim3(10, 8, 8), blk, 0, stream>>>(Ppb, vxtb, nullptr, nullptr, featb,
      588, C, 64, 64, 64, C, 1, 588LL * 64, 512LL * 64, 0LL, 588LL * 512);

  // merged arm q|k|vfe projection
  gemm128g<<<dim3(37, 8, 1), blk, 0, stream>>>(featb, qkw2t, qkvbias, nullptr, qkvfe,
      nullptr, nullptr, M_BND, 1024, C, C, C, 1024, 0, 0, 0, 0);

  // G[node] = vfe_node @ vfe_node^T  (49 x 49)
  gemm_mfma<<<dim3(1, 1, 96), blk, 0, stream>>>(qkvfe + 512, qkvfe + 512, nullptr, Gm, nullptr,
      D, D, C, 1024, 1024, D, 1, 49LL * 1024, 49LL * 1024, 0LL, 49LL * 49);

  // per-edge: inline QK^T + softmax + colsum@V (S1) + st2 via MFMA
  edge_finish<<<dim3(B * E), blk, 0, stream>>>(qkvfe, Gm, S1, eS);
  fe_k<<<dim3(2304), blk, 0, stream>>>(S1, eS, mask, fe);

  // two GNN layers
  for (int L = 0; L < 2; ++L) {
    const unsigned short* ABUVt = L ? ABUVt1 : ABUVt0;
    const unsigned short* wet   = L ? wet1 : wet0;
    {
      GJobs js{};
      js.j[0] = {f_v, ABUVt, nullptr, ABUV, nullptr, B * N, 2048, C, C, C, 2048, 0, 2};
      js.j[1] = {fe,  wet,   nullptr, EW,   nullptr, B * E, C,    C, C, C, C,    0, 18};
      js.ends[0] = 64; js.ends[1] = 208; js.ends[2] = 208; js.n = 2;
      gemm_jobs<<<dim3(208), blk, 0, stream>>>(js);
    }
    agg_stats<<<dim3(E), blk, 0, stream>>>(ABUV, EW, mu_e, rs_e);
    edmsg_k<<<dim3(B * N, 2), blk, 0, stream>>>(fe, ABUV, EW, mu_e, rs_e, pre, nps, npq);
    if (L == 0)
      xv_update<<<dim3((B * N * C + 255) / 256), blk, 0, stream>>>(f_v, pre, nps, npq);
  }

  out_k<<<dim3(B * N + B * E), blk, 0, stream>>>(f_v, pre, nps, npq, sc, fe, efc_w, efc_b, out);
}

// Round 10
// 220.873 us; speedup vs baseline: 1.0480x; 1.0480x over previous
//
#include <hip/hip_runtime.h>
#include <math.h>

namespace {

constexpr int B = 8, D = 49, C = 512, N = 12, H = 256, E = 144;
constexpr int M_BD  = B * D;        // 392
constexpr int M_BND = B * N * D;    // 4704
constexpr float BN_EPS = 1e-5f;
constexpr float ATT_SCALE = 0.0625f; // (C/2)^-0.5

typedef __attribute__((ext_vector_type(4))) float  floatx4;
typedef __attribute__((ext_vector_type(8))) short  shortx8;

__device__ inline unsigned short f2bf(float f) {
  unsigned u = __float_as_uint(f);
  return (unsigned short)((u + 0x7fffu + ((u >> 16) & 1u)) >> 16);
}
__device__ inline float bf2f(unsigned short u) {
  return __uint_as_float(((unsigned)u) << 16);
}

__device__ inline void gload16(const unsigned short* g, unsigned short* l) {
  __builtin_amdgcn_global_load_lds(
      (const __attribute__((address_space(1))) void*)g,
      (__attribute__((address_space(3))) void*)l, 16, 0, 0);
}

// ------- tcast (z<28): fp32 [512][Nn] -> bf16 [Nn][512]; z==28: castrow/bias/b2 -------
struct TCJobs {
  const float* src[28];
  unsigned short* dst[28];
  int nn[28];
};

__global__ __launch_bounds__(256)
void tcast_k(TCJobs jobs,
             const float* __restrict__ x, unsigned short* __restrict__ xb,
             const float* __restrict__ awv, unsigned short* __restrict__ armwvb,
             const float* __restrict__ bk, const float* __restrict__ bv,
             const float* __restrict__ bq2, const float* __restrict__ bk2,
             const float* __restrict__ arm_bv, const float* __restrict__ epw,
             const float* __restrict__ epb,
             float* __restrict__ kvbias, float* __restrict__ qkvbias)
{
  const int z = blockIdx.z;
  const int tid = threadIdx.x;
  if (z == 28) {
    int idx = (blockIdx.y * 16 + blockIdx.x) * 256 + tid;
    const int n1 = M_BD * C / 8;            // 25088
    const int n2 = n1 + C * C / 8;          // 57856
    if (idx < n1) {
      int i8 = idx * 8;
      float4 a = *reinterpret_cast<const float4*>(x + i8);
      float4 b = *reinterpret_cast<const float4*>(x + i8 + 4);
      shortx8 o;
      o[0]=(short)f2bf(a.x); o[1]=(short)f2bf(a.y); o[2]=(short)f2bf(a.z); o[3]=(short)f2bf(a.w);
      o[4]=(short)f2bf(b.x); o[5]=(short)f2bf(b.y); o[6]=(short)f2bf(b.z); o[7]=(short)f2bf(b.w);
      *reinterpret_cast<shortx8*>(xb + i8) = o;
    } else if (idx < n2) {
      int i8 = (idx - n1) * 8;
      float4 a = *reinterpret_cast<const float4*>(awv + i8);
      float4 b = *reinterpret_cast<const float4*>(awv + i8 + 4);
      shortx8 o;
      o[0]=(short)f2bf(a.x); o[1]=(short)f2bf(a.y); o[2]=(short)f2bf(a.z); o[3]=(short)f2bf(a.w);
      o[4]=(short)f2bf(b.x); o[5]=(short)f2bf(b.y); o[6]=(short)f2bf(b.z); o[7]=(short)f2bf(b.w);
      *reinterpret_cast<shortx8*>(armwvb + i8) = o;
    } else if (idx >= 58112 && idx < 58624) {
      int c = idx - 58112;
      float s = epb[c];
      for (int k = 0; k < C; ++k) s = fmaf(arm_bv[k], epw[k * C + c], s);
      qkvbias[512 + c] = s;
    }
    if (idx < 256) { kvbias[idx] = bk[idx]; qkvbias[idx] = bq2[idx]; qkvbias[256 + idx] = bk2[idx]; }
    if (idx < 512) kvbias[256 + idx] = bv[idx];
    return;
  }
  const float* src = jobs.src[z];
  unsigned short* dst = jobs.dst[z];
  const int Nn = jobs.nn[z];
  const int tx = blockIdx.x, ty = blockIdx.y;
  if (tx * 32 >= Nn) return;
  __shared__ float t[32][33];
  const int lr = tid >> 5, lc = tid & 31;
#pragma unroll
  for (int p = 0; p < 4; ++p) {
    int k = ty * 32 + p * 8 + lr;
    t[p * 8 + lr][lc] = src[(long long)k * Nn + tx * 32 + lc];
  }
  __syncthreads();
#pragma unroll
  for (int p = 0; p < 4; ++p) {
    int n = tx * 32 + p * 8 + lr;
    dst[(long long)n * 512 + ty * 32 + lc] = f2bf(t[lc][p * 8 + lr]);
  }
}

// ---------------- 64x64-tile bf16 MFMA GEMM body ----------------
__device__ __forceinline__
void gemm64_body(const void* __restrict__ Ain, const unsigned short* __restrict__ Bt,
                 const float* __restrict__ bp, float* __restrict__ co,
                 unsigned short* __restrict__ cb,
                 int M, int Nn, int K, int lda, int ldb, int ldc, int abf,
                 int bx, int by)
{
  const float* Af = abf ? nullptr : (const float*)Ain;
  const unsigned short* Ab = abf ? (const unsigned short*)Ain : nullptr;

  __shared__ short As[64 * 72];
  __shared__ short Bs[64 * 72];

  const int tid = threadIdx.x;
  const int row0 = bx * 64, col0 = by * 64;
  const int wid = tid >> 6, lane = tid & 63;
  const int wr = wid >> 1, wc = wid & 1;
  const int lr = lane & 15, lg = lane >> 4;

  floatx4 acc00 = {0.f,0.f,0.f,0.f}, acc01 = {0.f,0.f,0.f,0.f};
  floatx4 acc10 = {0.f,0.f,0.f,0.f}, acc11 = {0.f,0.f,0.f,0.f};

  const int r = tid >> 2, seg = tid & 3;
  const int gr = row0 + r, gn = col0 + r;
  short* aw = &As[r * 72 + seg * 16];
  short* bw = &Bs[r * 72 + seg * 16];
  const shortx8 zz = {0,0,0,0,0,0,0,0};

  for (int k0 = 0; k0 < K; k0 += 64) {
    shortx8 w0, w1;
    if (gr < M) {
      if (abf) {
        const shortx8* ap = reinterpret_cast<const shortx8*>(Ab + (long long)gr * lda + seg * 16 + k0);
        w0 = ap[0]; w1 = ap[1];
      } else {
        const float4* ap = reinterpret_cast<const float4*>(Af + (long long)gr * lda + seg * 16 + k0);
        float4 fa0 = ap[0], fa1 = ap[1], fa2 = ap[2], fa3 = ap[3];
        w0[0]=(short)f2bf(fa0.x); w0[1]=(short)f2bf(fa0.y); w0[2]=(short)f2bf(fa0.z); w0[3]=(short)f2bf(fa0.w);
        w0[4]=(short)f2bf(fa1.x); w0[5]=(short)f2bf(fa1.y); w0[6]=(short)f2bf(fa1.z); w0[7]=(short)f2bf(fa1.w);
        w1[0]=(short)f2bf(fa2.x); w1[1]=(short)f2bf(fa2.y); w1[2]=(short)f2bf(fa2.z); w1[3]=(short)f2bf(fa2.w);
        w1[4]=(short)f2bf(fa3.x); w1[5]=(short)f2bf(fa3.y); w1[6]=(short)f2bf(fa3.z); w1[7]=(short)f2bf(fa3.w);
      }
    } else { w0 = zz; w1 = zz; }
    const shortx8* bp8 = reinterpret_cast<const shortx8*>(Bt + (long long)gn * ldb + seg * 16 + k0);
    shortx8 b0v = bp8[0];
    shortx8 b1v = bp8[1];

    __syncthreads();
    *reinterpret_cast<shortx8*>(aw)     = w0;
    *reinterpret_cast<shortx8*>(aw + 8) = w1;
    *reinterpret_cast<shortx8*>(bw)     = b0v;
    *reinterpret_cast<shortx8*>(bw + 8) = b1v;
    __syncthreads();

#pragma unroll
    for (int kt = 0; kt < 2; ++kt) {
      shortx8 a0 = *reinterpret_cast<const shortx8*>(&As[(wr*32      + lr) * 72 + kt*32 + lg*8]);
      shortx8 a1 = *reinterpret_cast<const shortx8*>(&As[(wr*32 + 16 + lr) * 72 + kt*32 + lg*8]);
      shortx8 bb0 = *reinterpret_cast<const shortx8*>(&Bs[(wc*32      + lr) * 72 + kt*32 + lg*8]);
      shortx8 bb1 = *reinterpret_cast<const shortx8*>(&Bs[(wc*32 + 16 + lr) * 72 + kt*32 + lg*8]);
      acc00 = __builtin_amdgcn_mfma_f32_16x16x32_bf16(a0, bb0, acc00, 0, 0, 0);
      acc01 = __builtin_amdgcn_mfma_f32_16x16x32_bf16(a0, bb1, acc01, 0, 0, 0);
      acc10 = __builtin_amdgcn_mfma_f32_16x16x32_bf16(a1, bb0, acc10, 0, 0, 0);
      acc11 = __builtin_amdgcn_mfma_f32_16x16x32_bf16(a1, bb1, acc11, 0, 0, 0);
    }
  }

  const int colA = col0 + wc * 32 + lr;
  const int colB = colA + 16;
  const bool okA = colA < Nn, okB = colB < Nn;
  const float biasA = (bp && okA) ? bp[colA] : 0.f;
  const float biasB = (bp && okB) ? bp[colB] : 0.f;
  const int rb0 = row0 + wr * 32 + lg * 4;
  const int rb1 = rb0 + 16;
#pragma unroll
  for (int jj = 0; jj < 4; ++jj) {
    int ra = rb0 + jj, rb = rb1 + jj;
    float v00 = acc00[jj] + biasA, v01 = acc01[jj] + biasB;
    float v10 = acc10[jj] + biasA, v11 = acc11[jj] + biasB;
    if (ra < M) {
      if (co) { if (okA) co[(long long)ra * ldc + colA] = v00;
                if (okB) co[(long long)ra * ldc + colB] = v01; }
      if (cb) { if (okA) cb[(long long)ra * ldc + colA] = f2bf(v00);
                if (okB) cb[(long long)ra * ldc + colB] = f2bf(v01); }
    }
    if (rb < M) {
      if (co) { if (okA) co[(long long)rb * ldc + colA] = v10;
                if (okB) co[(long long)rb * ldc + colB] = v11; }
      if (cb) { if (okA) cb[(long long)rb * ldc + colA] = f2bf(v10);
                if (okB) cb[(long long)rb * ldc + colB] = f2bf(v11); }
    }
  }
}

// ---------------- z-batched 64² GEMM ----------------
__global__ __launch_bounds__(256)
void gemm_mfma(const void* __restrict__ Ain, const unsigned short* __restrict__ Bt,
               const float* __restrict__ bias, float* __restrict__ Co,
               unsigned short* __restrict__ Cb,
               int M, int Nn, int K, int lda, int ldb, int ldc, int abf,
               long long sA, long long sB, long long sBias, long long sC)
{
  const int z = blockIdx.z;
  const void* A = abf ? (const void*)((const unsigned short*)Ain + z * sA)
                      : (const void*)((const float*)Ain + z * sA);
  gemm64_body(A, Bt + z * sB, bias ? bias + z * sBias : nullptr,
              Co ? Co + z * sC : nullptr, Cb ? Cb + z * sC : nullptr,
              M, Nn, K, lda, ldb, ldc, abf, blockIdx.x, blockIdx.y);
}

// ---------------- multi-job 64² GEMM ----------------
struct GJob {
  const void* A; const unsigned short* B; const float* bias;
  float* Co; unsigned short* Cb;
  int M, Nn, K, lda, ldb, ldc, abf, tx;
};
struct GJobs { GJob j[3]; int ends[3]; int n; };

__global__ __launch_bounds__(256)
void gemm_jobs(GJobs js)
{
  const int bid = blockIdx.x;
#pragma unroll
  for (int q = 0; q < 3; ++q) {
    if (q < js.n && bid < js.ends[q]) {
      int start = q ? js.ends[q - 1] : 0;
      int local = bid - start;
      const GJob& J = js.j[q];
      gemm64_body(J.A, J.B, J.bias, J.Co, J.Cb,
                  J.M, J.Nn, J.K, J.lda, J.ldb, J.ldc, J.abf,
                  local % J.tx, local / J.tx);
      return;
    }
  }
}

// ------- 128²-tile GEMM body, global_load_lds staging; optional BN-stat partials -------
__device__ __forceinline__
void g128_body(const unsigned short* __restrict__ Ab, const unsigned short* __restrict__ Bt,
               const float* __restrict__ bp, float* __restrict__ co,
               unsigned short* __restrict__ cb, float* __restrict__ psb, float* __restrict__ pqb,
               int M, int Nn, int K, int lda, int ldb, int ldc, int bx, int by)
{
  __shared__ unsigned short As[128 * 64];
  __shared__ unsigned short Bs[128 * 64];

  const int tid = threadIdx.x;
  const int row0 = bx * 128, col0 = by * 128;
  const int wid = tid >> 6, lane = tid & 63;
  const int wr = wid >> 1, wc = wid & 1;
  const int lr = lane & 15, lg = lane >> 4;

  floatx4 acc[4][4];
#pragma unroll
  for (int mf = 0; mf < 4; ++mf)
#pragma unroll
    for (int nf = 0; nf < 4; ++nf) acc[mf][nf] = floatx4{0.f,0.f,0.f,0.f};

  const int rsub = tid >> 3;
  const int csub = (tid & 7) * 8;

  for (int k0 = 0; k0 < K; k0 += 64) {
    __syncthreads();
#pragma unroll
    for (int it = 0; it < 4; ++it) {
      int r = it * 32 + rsub;
      gload16(Ab + (long long)(row0 + r) * lda + k0 + csub, As + it * 2048 + tid * 8);
      gload16(Bt + (long long)(col0 + r) * ldb + k0 + csub, Bs + it * 2048 + tid * 8);
    }
    __syncthreads();

#pragma unroll
    for (int kt = 0; kt < 2; ++kt) {
      shortx8 af[4], bf[4];
#pragma unroll
      for (int mf = 0; mf < 4; ++mf)
        af[mf] = *reinterpret_cast<const shortx8*>(&As[(wr*64 + mf*16 + lr) * 64 + kt*32 + lg*8]);
#pragma unroll
      for (int nf = 0; nf < 4; ++nf)
        bf[nf] = *reinterpret_cast<const shortx8*>(&Bs[(wc*64 + nf*16 + lr) * 64 + kt*32 + lg*8]);
#pragma unroll
      for (int mf = 0; mf < 4; ++mf)
#pragma unroll
        for (int nf = 0; nf < 4; ++nf)
          acc[mf][nf] = __builtin_amdgcn_mfma_f32_16x16x32_bf16(af[mf], bf[nf], acc[mf][nf], 0, 0, 0);
    }
  }

#pragma unroll
  for (int nf = 0; nf < 4; ++nf) {
    const int col = col0 + wc * 64 + nf * 16 + lr;
    if (col >= Nn) continue;
    const float bv = bp ? bp[col] : 0.f;
#pragma unroll
    for (int mf = 0; mf < 4; ++mf) {
      const int rbase = row0 + wr * 64 + mf * 16 + lg * 4;
#pragma unroll
      for (int jj = 0; jj < 4; ++jj) {
        int row = rbase + jj;
        if (row >= M) continue;
        float v = acc[mf][nf][jj] + bv;
        if (co) co[(long long)row * ldc + col] = v;
        if (cb) cb[(long long)row * ldc + col] = f2bf(v);
      }
    }
  }

  if (psb) {
    __syncthreads();
    float* sb = (float*)As;
    sb[tid] = 0.f;
    __syncthreads();
#pragma unroll
    for (int nf = 0; nf < 4; ++nf) {
      const int lcol = wc * 64 + nf * 16 + lr;
      const int col = col0 + lcol;
      float s = 0.f, q = 0.f;
      if (col < Nn) {
        const float bv = bp ? bp[col] : 0.f;
#pragma unroll
        for (int mf = 0; mf < 4; ++mf) {
          const int rbase = row0 + wr * 64 + mf * 16 + lg * 4;
#pragma unroll
          for (int jj = 0; jj < 4; ++jj) {
            if (rbase + jj < M) { float v = acc[mf][nf][jj] + bv; s += v; q += v * v; }
          }
        }
      }
      atomicAdd(&sb[lcol], s);
      atomicAdd(&sb[128 + lcol], q);
    }
    __syncthreads();
    if (tid < 128) {
      psb[col0 + tid] = sb[tid];
      pqb[col0 + tid] = sb[128 + tid];
    }
  }
}

__global__ __launch_bounds__(256)
void gemm128g(const unsigned short* __restrict__ Ab, const unsigned short* __restrict__ Bt,
              const float* __restrict__ bias, float* __restrict__ Co,
              unsigned short* __restrict__ Cb, float* __restrict__ ps, float* __restrict__ pq,
              int M, int Nn, int K, int lda, int ldb, int ldc,
              long long sA, long long sB, long long sBias, long long sC)
{
  const int z = blockIdx.z;
  long long so = ((long long)blockIdx.x * gridDim.z + z) * ldc;
  g128_body(Ab + z * sA, Bt + z * sB, bias ? bias + z * sBias : nullptr,
            Co ? Co + z * sC : nullptr, Cb ? Cb + z * sC : nullptr,
            ps ? ps + so : nullptr, pq ? pq + so : nullptr,
            M, Nn, K, lda, ldb, ldc, blockIdx.x, blockIdx.y);
}

// ---------------- Sc (128² body) + Gm (64² body) in one launch ----------------
__global__ __launch_bounds__(256)
void scgm_k(const unsigned short* __restrict__ qkvfe, float* __restrict__ Sc,
            float* __restrict__ Gm)
{
  const int bid = blockIdx.x;
  if (bid < 200) {
    int z = bid / 25, rem = bid % 25;
    g128_body(qkvfe + (long long)z * 588 * 1024, qkvfe + 256 + (long long)z * 588 * 1024,
              nullptr, Sc + (long long)z * 588 * 588, nullptr, nullptr, nullptr,
              588, 588, H, 1024, 1024, 588, rem % 5, rem / 5);
  } else {
    int z = bid - 200;
    const unsigned short* vp = qkvfe + 512 + (long long)z * 49 * 1024;
    gemm64_body(vp, vp, nullptr, Gm + (long long)z * 2401, nullptr,
                D, D, C, 1024, 1024, D, 1, 0, 0);
  }
}

// ------- f_u = relu(norm(h)) -> bf16, f_v = mean_d f_u (4-slice stats fold) -------
__global__ __launch_bounds__(256)
void fu_fv(const float* __restrict__ h, const float* __restrict__ ps,
           const float* __restrict__ pq, unsigned short* __restrict__ fub,
           float* __restrict__ fv)
{
  const int bid = blockIdx.x;
  const int b = bid / N, n = bid % N;
  const int c = blockIdx.y * 256 + threadIdx.x;
  const int idx = n * C + c;
  float s = 0.f, q = 0.f;
#pragma unroll
  for (int sl = 0; sl < 4; ++sl) { s += ps[sl * (N * C) + idx]; q += pq[sl * (N * C) + idx]; }
  float m = s / (float)M_BD;
  float rv = rsqrtf(q / (float)M_BD - m * m + BN_EPS);
  float acc = 0.f;
  for (int d = 0; d < D; ++d) {
    float v = h[((long long)n * M_BD + b * D + d) * C + c];
    v = fmaxf((v - m) * rv, 0.f);
    fub[((long long)bid * D + d) * C + c] = f2bf(v);
    acc += v;
  }
  fv[(long long)bid * C + c] = acc * (1.0f / (float)D);
}

// -- fused: fam softmax (0..18) + vx transpose (19..82) + cosine mask (83..90) --
__global__ __launch_bounds__(256)
void softvxt_k(const float* __restrict__ Sf, unsigned short* __restrict__ Ppb,
               const unsigned short* __restrict__ kvx, unsigned short* __restrict__ vxtb,
               const float* __restrict__ fv, float* __restrict__ maskp)
{
  const int tid = threadIdx.x;
  if (blockIdx.x < 19) {
    int row = blockIdx.x * 256 + tid;
    if (row >= M_BND) return;
    const float* p = Sf + (long long)row * 49;
    float v[49];
    float m = -1e30f;
#pragma unroll
    for (int j = 0; j < 49; ++j) { v[j] = p[j] * ATT_SCALE; m = fmaxf(m, v[j]); }
    float s = 0.f;
#pragma unroll
    for (int j = 0; j < 49; ++j) { v[j] = __expf(v[j] - m); s += v[j]; }
    float inv = 1.f / s;
    unsigned short* o = Ppb + (long long)row * 64;
#pragma unroll
    for (int j = 0; j < 49; ++j) o[j] = f2bf(v[j] * inv);
#pragma unroll
    for (int j = 49; j < 64; ++j) o[j] = 0;
    return;
  }
  if (blockIdx.x < 83) {
    const int i = blockIdx.x - 19;
    const int b = i >> 3, cc = i & 7;
    __shared__ unsigned short t[49][65];
    for (int idx = tid; idx < 49 * 64; idx += 256) {
      int rr = idx >> 6, k = idx & 63;
      t[rr][k] = kvx[(long long)(b * 49 + rr) * 768 + 256 + cc * 64 + k];
    }
    __syncthreads();
    for (int idx = tid; idx < 64 * 64; idx += 256) {
      int n = idx >> 6, kk = idx & 63;
      vxtb[((long long)b * 512 + cc * 64 + n) * 64 + kk] = (kk < 49) ? t[kk][n] : (unsigned short)0;
    }
    return;
  }
  const int b = blockIdx.x - 83;
  __shared__ float fl[N][C];
  __shared__ float adj[N][N];
  __shared__ float nrm[N];
  __shared__ float dis[N];
  for (int idx = tid; idx < N * C; idx += 256)
    fl[idx / C][idx % C] = fv[(long long)b * N * C + idx];
  __syncthreads();
  if (tid < N * N) {
    int i = tid / N, j = tid % N;
    float s = 0.f;
    for (int k = 0; k < C; ++k) s += fl[i][k] * fl[j][k];
    adj[i][j] = s;
  }
  __syncthreads();
  if (tid < N) nrm[tid] = fmaxf(sqrtf(adj[tid][tid]), 1e-12f);
  __syncthreads();
  if (tid < N * N) {
    int i = tid / N, j = tid % N;
    adj[i][j] = adj[i][j] / (nrm[i] * nrm[j]);
  }
  __syncthreads();
  if (tid < N) {
    float s = 0.f;
    for (int j = 0; j < N; ++j) s += adj[tid][j];
    dis[tid] = rsqrtf(s);
  }
  __syncthreads();
  if (tid < N * N) {
    int i = tid / N, j = tid % N;
    maskp[b * E + tid] = adj[i][j] * dis[i] * dis[j];
  }
}

// ------- edge finish: softmax + colsum@V (S1, 2-wide) + st2 = <A^T A, G> via MFMA -------
__global__ __launch_bounds__(256)
void edge_finish(const float* __restrict__ Sc, const float* __restrict__ G,
                 const unsigned short* __restrict__ qkvfe,
                 float* __restrict__ S1, float* __restrict__ eS)
{
  const int bid = blockIdx.x;           // b*E + e
  const int b = bid / E, e = bid % E;
  const int i = e / N, j = e % N;
  const float* Scb = Sc + (long long)b * 588 * 588 + (long long)(j * 49) * 588 + i * 49;
  const float* Gp  = G + (long long)(b * N + i) * 2401;
  const unsigned short* Vp = qkvfe + (long long)(b * N + i) * D * 1024 + 512;

  __shared__ float aT[49][53];          // aT[dj][di] = probs[di][dj]
  __shared__ float g[49][53];
  __shared__ unsigned short abT[64][72];
  __shared__ float ws[52];
  __shared__ float r0[4], r1[4];
  const int tid = threadIdx.x;
  const int wid = tid >> 6, lane = tid & 63;
  const int lr = lane & 15, lg = lane >> 4;

  for (int idx = tid; idx < 49 * 49; idx += 256) {
    int di = idx / 49, dj = idx - di * 49;
    aT[dj][di] = Scb[di * 588 + dj] * ATT_SCALE;
    g[di][dj] = Gp[idx];
  }
  __syncthreads();
  if (tid < D) {
    float m = -1e30f;
    for (int jj = 0; jj < D; ++jj) m = fmaxf(m, aT[jj][tid]);
    float s = 0.f;
    for (int jj = 0; jj < D; ++jj) { float ev = __expf(aT[jj][tid] - m); aT[jj][tid] = ev; s += ev; }
    float inv = 1.f / s;
    for (int jj = 0; jj < D; ++jj) aT[jj][tid] *= inv;
  }
  __syncthreads();
  for (int idx = tid; idx < 64 * 64; idx += 256) {
    int dj = idx >> 6, di = idx & 63;
    float v = (dj < D && di < D) ? aT[dj][di] : 0.f;
    abT[dj][di] = f2bf(v);
  }
  if (tid < D) {
    float s = 0.f;
    for (int di = 0; di < D; ++di) s += aT[tid][di];
    ws[tid] = s;
  }
  __syncthreads();

  floatx4 acc[4];
#pragma unroll
  for (int tk = 0; tk < 4; ++tk) acc[tk] = floatx4{0.f,0.f,0.f,0.f};
  shortx8 af0 = *reinterpret_cast<const shortx8*>(&abT[wid * 16 + lr][lg * 8]);
  shortx8 af1 = *reinterpret_cast<const shortx8*>(&abT[wid * 16 + lr][32 + lg * 8]);
#pragma unroll
  for (int tk = 0; tk < 4; ++tk) {
    shortx8 bf0v = *reinterpret_cast<const shortx8*>(&abT[tk * 16 + lr][lg * 8]);
    shortx8 bf1v = *reinterpret_cast<const shortx8*>(&abT[tk * 16 + lr][32 + lg * 8]);
    acc[tk] = __builtin_amdgcn_mfma_f32_16x16x32_bf16(af0, bf0v, acc[tk], 0, 0, 0);
    acc[tk] = __builtin_amdgcn_mfma_f32_16x16x32_bf16(af1, bf1v, acc[tk], 0, 0, 0);
  }
  float st2 = 0.f;
#pragma unroll
  for (int tk = 0; tk < 4; ++tk) {
    int kcol = tk * 16 + lr;
#pragma unroll
    for (int rg = 0; rg < 4; ++rg) {
      int jrow = wid * 16 + lg * 4 + rg;
      if (jrow < D && kcol < D) st2 = fmaf(acc[tk][rg], g[jrow][kcol], st2);
    }
  }

  // S1 = colsum(A) @ V  — 2 bf16 per lane per row
  const unsigned* Vp32 = reinterpret_cast<const unsigned*>(Vp);
  float s1a = 0.f, s1b = 0.f;
  for (int dk = 0; dk < D; ++dk) {
    unsigned u = Vp32[dk * 512 + tid];
    float w = ws[dk];
    s1a = fmaf(w, bf2f((unsigned short)(u & 0xffffu)), s1a);
    s1b = fmaf(w, bf2f((unsigned short)(u >> 16)), s1b);
  }
  S1[(long long)bid * C + 2 * tid]     = s1a;
  S1[(long long)bid * C + 2 * tid + 1] = s1b;
  float st = s1a + s1b;

  for (int off = 32; off; off >>= 1) { st += __shfl_down(st, off); st2 += __shfl_down(st2, off); }
  if (lane == 0) { r0[wid] = st; r1[wid] = st2; }
  __syncthreads();
  if (tid == 0) {
    eS[bid * 2 + 0] = r0[0] + r0[1] + r0[2] + r0[3];
    eS[bid * 2 + 1] = r1[0] + r1[1] + r1[2] + r1[3];
  }
}

// ---------------- f_e = (S1/D - me)*rve * mask (me/rve computed inline) ----------------
__global__ __launch_bounds__(256)
void fe_k(const float* __restrict__ S1, const float* __restrict__ eS,
          const float* __restrict__ maskp, float* __restrict__ fe)
{
  __shared__ float csh[3];
  long long idx0 = (long long)blockIdx.x * 256;
  long long be = idx0 / C;
  int e = (int)(be % E);
  if (threadIdx.x == 0) {
    float s = 0.f, q = 0.f;
    for (int b = 0; b < B; ++b) { s += eS[(b * E + e) * 2]; q += eS[(b * E + e) * 2 + 1]; }
    const float inv = 1.f / (float)(B * D * C);
    float m = s * inv;
    csh[0] = m;
    csh[1] = rsqrtf(q * inv - m * m + BN_EPS);
    csh[2] = maskp[be];
  }
  __syncthreads();
  long long idx = idx0 + threadIdx.x;
  fe[idx] = (S1[idx] * (1.0f / (float)D) - csh[0]) * csh[1] * csh[2];
}

// ---------------- GNN: BN stats per e over agg = A[i]+B[j]+EW[e] ----------------
__global__ __launch_bounds__(256)
void agg_stats(const float* __restrict__ ABUV, const float* __restrict__ EW,
               float* __restrict__ mu_e, float* __restrict__ rs_e)
{
  const int e = blockIdx.x;
  const int i = e / N, j = e % N;
  const int tid = threadIdx.x;
  float s = 0.f, q = 0.f;
  for (int idx = tid; idx < B * C; idx += 256) {
    int b = idx >> 9, c = idx & 511;
    float v = ABUV[(long long)(b * N + i) * 2048 + c]
            + ABUV[(long long)(b * N + j) * 2048 + 512 + c]
            + EW[((long long)b * E + e) * C + c];
    s += v; q += v * v;
  }
  for (int off = 32; off; off >>= 1) { s += __shfl_down(s, off); q += __shfl_down(q, off); }
  __shared__ float r0[4], r1[4];
  int wid = tid >> 6, lane = tid & 63;
  if (lane == 0) { r0[wid] = s; r1[wid] = q; }
  __syncthreads();
  if (tid == 0) {
    float ss = r0[0] + r0[1] + r0[2] + r0[3];
    float qq = r1[0] + r1[1] + r1[2] + r1[3];
    float m = ss / (float)(B * C);
    mu_e[e] = m;
    rs_e[e] = rsqrtf(qq / (float)(B * C) - m * m + BN_EPS);
  }
}

// -- fused: ed update + msg + pre + node-BN partials; grid (B*N, 2), one c per thread --
__global__ __launch_bounds__(256)
void edmsg_k(float* __restrict__ fe, const float* __restrict__ ABUV,
             const float* __restrict__ EW, const float* __restrict__ mu_e,
             const float* __restrict__ rs_e, float* __restrict__ pre,
             float* __restrict__ nps, float* __restrict__ npq)
{
  const int bid = blockIdx.x;
  const int b = bid / N, i = bid % N;
  const int half = blockIdx.y;
  const int tid = threadIdx.x;
  const int c = half * 256 + tid;

  float ai = ABUV[(long long)(b * N + i) * 2048 + c];
  float sv[N];
  float m = -1e30f;
#pragma unroll
  for (int jn = 0; jn < N; ++jn) {
    int e = i * N + jn;
    float v = ai + ABUV[(long long)(b * N + jn) * 2048 + 512 + c]
            + EW[((long long)b * E + e) * C + c];
    v = (v - mu_e[e]) * rs_e[e];
    float ed = fe[((long long)b * E + e) * C + c] + fmaxf(v, 0.f);
    fe[((long long)b * E + e) * C + c] = ed;
    float sg = 1.f / (1.f + __expf(-ed));
    sv[jn] = sg; m = fmaxf(m, sg);
  }
  float sum = 0.f;
#pragma unroll
  for (int jn = 0; jn < N; ++jn) { float ev = __expf(sv[jn] - m); sv[jn] = ev; sum += ev; }
  float acc = 0.f;
#pragma unroll
  for (int jn = 0; jn < N; ++jn)
    acc = fmaf(sv[jn], ABUV[(long long)(b * N + jn) * 2048 + 1536 + c], acc);
  acc /= (sum * (float)N);
  float pv = ABUV[(long long)bid * 2048 + 1024 + c] + acc;
  pre[(long long)bid * C + c] = pv;
  float ls = pv, lq = pv * pv;
  for (int off = 32; off; off >>= 1) { ls += __shfl_down(ls, off); lq += __shfl_down(lq, off); }
  __shared__ float r0[4], r1[4];
  int wid = tid >> 6, lane = tid & 63;
  if (lane == 0) { r0[wid] = ls; r1[wid] = lq; }
  __syncthreads();
  if (tid == 0) {
    nps[(i * B + b) * 2 + half] = r0[0] + r0[1] + r0[2] + r0[3];
    npq[(i * B + b) * 2 + half] = r1[0] + r1[1] + r1[2] + r1[3];
  }
}

__global__ void xv_update(float* __restrict__ xv, const float* __restrict__ pre,
                          const float* __restrict__ nps, const float* __restrict__ npq)
{
  long long idx = (long long)blockIdx.x * 256 + threadIdx.x;
  if (idx >= (long long)B * N * C) return;
  int i = (int)((idx / C) % N);
  float s = 0.f, q = 0.f;
#pragma unroll
  for (int t = 0; t < B * 2; ++t) { s += nps[i * B * 2 + t]; q += npq[i * B * 2 + t]; }
  float mu = s * (1.f / (float)(B * C));
  float rs = rsqrtf(q * (1.f / (float)(B * C)) - mu * mu + BN_EPS);
  float v = xv[idx] + (pre[idx] - mu) * rs;
  xv[idx] = fmaxf(v, 0.f);
}

// ------- outputs (final xv_update folded into cl part) -------
__global__ __launch_bounds__(256)
void out_k(const float* __restrict__ xv, const float* __restrict__ pre,
           const float* __restrict__ nps, const float* __restrict__ npq,
           const float* __restrict__ sc,
           const float* __restrict__ ed, const float* __restrict__ w,
           const float* __restrict__ bias, float* __restrict__ out)
{
  const int bid = blockIdx.x;
  const int tid = threadIdx.x;
  int wid = tid >> 6, lane = tid & 63;
  if (bid < B * N) {
    const int b = bid / N, i = bid % N;
    float s = 0.f, q = 0.f;
#pragma unroll
    for (int t = 0; t < B * 2; ++t) { s += nps[i * B * 2 + t]; q += npq[i * B * 2 + t]; }
    float mu = s * (1.f / (float)(B * C));
    float rs = rsqrtf(q * (1.f / (float)(B * C)) - mu * mu + BN_EPS);
    float sxx = 0.f, sss = 0.f, sxs = 0.f;
    for (int c = tid; c < C; c += 256) {
      float xvv = fmaxf(xv[(long long)bid * C + c] + (pre[(long long)bid * C + c] - mu) * rs, 0.f);
      float scv = fmaxf(sc[i * C + c], 0.f);
      sxx += xvv * xvv; sss += scv * scv; sxs += xvv * scv;
    }
    for (int off = 32; off; off >>= 1) {
      sxx += __shfl_down(sxx, off);
      sss += __shfl_down(sss, off);
      sxs += __shfl_down(sxs, off);
    }
    __shared__ float r0[4], r1[4], r2[4];
    if (lane == 0) { r0[wid] = sxx; r1[wid] = sss; r2[wid] = sxs; }
    __syncthreads();
    if (tid == 0) {
      float a = r0[0] + r0[1] + r0[2] + r0[3];
      float ss = r1[0] + r1[1] + r1[2] + r1[3];
      float p = r2[0] + r2[1] + r2[2] + r2[3];
      float nx = fmaxf(sqrtf(a), 1e-12f);
      float ns = fmaxf(sqrtf(ss), 1e-12f);
      out[b * N + i] = p / (nx * ns);
    }
  } else {
    const int eb = bid - B * N;
    float a0 = 0, a1 = 0, a2 = 0, a3 = 0;
    for (int c = tid; c < C; c += 256) {
      float v = ed[(long long)eb * C + c];
      a0 = fmaf(v, w[c * 4 + 0], a0);
      a1 = fmaf(v, w[c * 4 + 1], a1);
      a2 = fmaf(v, w[c * 4 + 2], a2);
      a3 = fmaf(v, w[c * 4 + 3], a3);
    }
    for (int off = 32; off; off >>= 1) {
      a0 += __shfl_down(a0, off);
      a1 += __shfl_down(a1, off);
      a2 += __shfl_down(a2, off);
      a3 += __shfl_down(a3, off);
    }
    __shared__ float r[4][4];
    if (lane == 0) { r[wid][0] = a0; r[wid][1] = a1; r[wid][2] = a2; r[wid][3] = a3; }
    __syncthreads();
    if (tid < 4) {
      float sr = r[0][tid] + r[1][tid] + r[2][tid] + r[3][tid];
      out[B * N + eb * 4 + tid] = sr + bias[tid];
    }
  }
}

} // namespace

extern "C" void kernel_launch(void* const* d_in, const int* in_sizes, int n_in,
                              void* d_out, int out_size, void* d_ws, size_t ws_size,
                              hipStream_t stream)
{
  (void)in_sizes; (void)n_in; (void)out_size; (void)ws_size;
  const float* x      = (const float*)d_in[0];
  const float* Wc     = (const float*)d_in[1];
  const float* bc     = (const float*)d_in[2];
  const float* fam_wq = (const float*)d_in[3];
  const float* fam_bq = (const float*)d_in[4];
  const float* fam_wk = (const float*)d_in[5];
  const float* fam_bk = (const float*)d_in[6];
  const float* fam_wv = (const float*)d_in[7];
  const float* fam_bv = (const float*)d_in[8];
  const float* arm_wq = (const float*)d_in[9];
  const float* arm_bq = (const float*)d_in[10];
  const float* arm_wk = (const float*)d_in[11];
  const float* arm_bk = (const float*)d_in[12];
  const float* arm_wv = (const float*)d_in[13];
  const float* arm_bv = (const float*)d_in[14];
  const float* ep_w   = (const float*)d_in[15];
  const float* ep_b   = (const float*)d_in[16];
  const float* gw[10] = {
    (const float*)d_in[17], (const float*)d_in[18], (const float*)d_in[19],
    (const float*)d_in[20], (const float*)d_in[21],
    (const float*)d_in[22], (const float*)d_in[23], (const float*)d_in[24],
    (const float*)d_in[25], (const float*)d_in[26]};
  const float* sc     = (const float*)d_in[27];
  const float* efc_w  = (const float*)d_in[28];
  const float* efc_b  = (const float*)d_in[29];
  float* out = (float*)d_out;

  char* wsb = (char*)d_ws;
  size_t off = 0;
  auto allocf = [&](size_t n) { float* p = (float*)(wsb + off); off += ((n * 4 + 255) / 256) * 256; return p; };
  auto allocu = [&](size_t n) { unsigned short* p = (unsigned short*)(wsb + off); off += ((n * 2 + 255) / 256) * 256; return p; };

  // region_a: h_t (2.41M f) early; Sc (2.77M f) later (h_t dead after fu_fv)
  float* region_a = allocf(2766336);
  float* h_t = region_a;
  float* Sc  = region_a;

  float* bnp_s = allocf(24576);            // 4 slices x N x C
  float* bnp_q = allocf(24576);
  float* f_v   = allocf(49152);
  float* Sf    = allocf(230496);           // 8*588*49
  float* Gm    = allocf(230496);           // 96*49*49
  float* S1    = allocf(589824);
  float* fe    = allocf(589824);
  float* EW    = allocf(589824);
  float* eS    = allocf(2304);
  float* mask  = allocf(1152);
  float* ABUV  = allocf(196608);
  float* pre   = allocf(49152);
  float* mu_e  = allocf(144);
  float* rs_e  = allocf(144);
  float* nps   = allocf(192);
  float* npq   = allocf(192);
  float* kvbias  = allocf(768);
  float* qkvbias = allocf(1024);           // [arm_bq|arm_bk|b2]

  unsigned short* Wct    = allocu(3145728);
  unsigned short* famqt  = allocu(131072);
  unsigned short* kvwt   = allocu(393216);   // [768][512]: fam_wk | fam_wv
  unsigned short* qkw2t  = allocu(524288);   // [1024][512]: arm_wq | arm_wk | W2^T
  unsigned short* epwt   = allocu(262144);
  unsigned short* armwvb = allocu(262144);   // arm_wv row-major bf16
  unsigned short* wet0   = allocu(262144);
  unsigned short* wet1   = allocu(262144);
  unsigned short* ABUVt0 = allocu(1048576);
  unsigned short* ABUVt1 = allocu(1048576);
  unsigned short* xb     = allocu(262144);   // [512][512] (rows padded for gload)
  unsigned short* fub    = allocu(2408448);
  unsigned short* q1b    = allocu(1204224);  // [4704][256]
  unsigned short* kxvx_b = allocu(350208);   // [456][768] (pad rows for B overread)
  unsigned short* Ppb    = allocu(301056);   // [4704][64]
  unsigned short* vxtb   = allocu(262144);   // [8][512][64]
  unsigned short* featb  = allocu(2424832);  // [4736][512] (rows padded for gload)
  unsigned short* qkvfe  = allocu(4915200);  // [4800][1024]: q|k|vfe (pad rows)

  dim3 blk(256);

  // -------- weight transpose+cast (28 jobs) + castrow/bias/b2 branch (z=28) --------
  TCJobs tj{};
  int jn = 0;
  for (int n = 0; n < 12; ++n) { tj.src[jn] = Wc + (size_t)n * C * C; tj.dst[jn] = Wct + (size_t)n * C * C; tj.nn[jn] = C; ++jn; }
  tj.src[jn] = fam_wq; tj.dst[jn] = famqt;             tj.nn[jn] = H; ++jn;
  tj.src[jn] = fam_wk; tj.dst[jn] = kvwt;              tj.nn[jn] = H; ++jn;
  tj.src[jn] = fam_wv; tj.dst[jn] = kvwt + 256 * 512;  tj.nn[jn] = C; ++jn;
  tj.src[jn] = arm_wq; tj.dst[jn] = qkw2t;             tj.nn[jn] = H; ++jn;
  tj.src[jn] = arm_wk; tj.dst[jn] = qkw2t + 256 * 512; tj.nn[jn] = H; ++jn;
  tj.src[jn] = ep_w;   tj.dst[jn] = epwt;              tj.nn[jn] = C; ++jn;
  tj.src[jn] = gw[2];  tj.dst[jn] = wet0;              tj.nn[jn] = C; ++jn;
  tj.src[jn] = gw[7];  tj.dst[jn] = wet1;              tj.nn[jn] = C; ++jn;
  tj.src[jn] = gw[0];  tj.dst[jn] = ABUVt0;               tj.nn[jn] = C; ++jn;
  tj.src[jn] = gw[1];  tj.dst[jn] = ABUVt0 + 1 * C * C;   tj.nn[jn] = C; ++jn;
  tj.src[jn] = gw[3];  tj.dst[jn] = ABUVt0 + 2 * C * C;   tj.nn[jn] = C; ++jn;
  tj.src[jn] = gw[4];  tj.dst[jn] = ABUVt0 + 3 * C * C;   tj.nn[jn] = C; ++jn;
  tj.src[jn] = gw[5];  tj.dst[jn] = ABUVt1;               tj.nn[jn] = C; ++jn;
  tj.src[jn] = gw[6];  tj.dst[jn] = ABUVt1 + 1 * C * C;   tj.nn[jn] = C; ++jn;
  tj.src[jn] = gw[8];  tj.dst[jn] = ABUVt1 + 2 * C * C;   tj.nn[jn] = C; ++jn;
  tj.src[jn] = gw[9];  tj.dst[jn] = ABUVt1 + 3 * C * C;   tj.nn[jn] = C; ++jn;
  tcast_k<<<dim3(16, 16, 29), blk, 0, stream>>>(tj, x, xb, arm_wv, armwvb,
      fam_bk, fam_bv, arm_bq, arm_bk, arm_bv, ep_w, ep_b, kvbias, qkvbias);

  // h[n] = x @ Wc[n] + bc[n]  (128² gload tiles, BN stats fused)
  gemm128g<<<dim3(4, 4, 12), blk, 0, stream>>>(xb, Wct, bc, h_t, nullptr, bnp_s, bnp_q,
      M_BD, C, C, C, C, C, 0LL, (long long)C * C, (long long)C, (long long)M_BD * C);
  fu_fv<<<dim3(B * N, 2), blk, 0, stream>>>(h_t, bnp_s, bnp_q, fub, f_v);

  // batched: q1 (fam q), kxvx (fam k|v), W2^T = ep_w^T @ arm_wv^T
  {
    GJobs js{};
    js.j[0] = {fub,  famqt,  fam_bq, nullptr, q1b,            M_BND, H,   C, C, C, H,   1, 74};
    js.j[1] = {xb,   kvwt,   kvbias, nullptr, kxvx_b,         M_BD,  768, C, C, C, 768, 1, 7};
    js.j[2] = {epwt, armwvb, nullptr, nullptr, qkw2t + 512 * 512, C,  C,   C, C, C, C,   1, 8};
    js.ends[0] = 296; js.ends[1] = 380; js.ends[2] = 444; js.n = 3;
    gemm_jobs<<<dim3(444), blk, 0, stream>>>(js);
  }
  // Sf[b] = q1[b] @ kx[b]^T  (588 x 49)
  gemm_mfma<<<dim3(10, 1, 8), blk, 0, stream>>>(q1b, kxvx_b, nullptr, Sf, nullptr,
      588, 49, H, H, 768, 49, 1, 588LL * 256, 49LL * 768, 0LL, 588LL * 49);
  softvxt_k<<<dim3(91), blk, 0, stream>>>(Sf, Ppb, kxvx_b, vxtb, f_v, mask);
  // feat[b] = P[b] @ vx[b]  (588 x 512, K=64)
  gemm_mfma<<<dim3(10, 8, 8), blk, 0, stream>>>(Ppb, vxtb, nullptr, nullptr, featb,
      588, C, 64, 64, 64, C, 1, 588LL * 64, 512LL * 64, 0LL, 588LL * 512);

  // merged arm q|k|vfe projection
  gemm128g<<<dim3(37, 8, 1), blk, 0, stream>>>(featb, qkw2t, qkvbias, nullptr, qkvfe,
      nullptr, nullptr, M_BND, 1024, C, C, C, 1024, 0, 0, 0, 0);

  // Sc[b] = qf[b] @ kf[b]^T (128² tiles) + G[node] = vfe vfe^T (64² tiles), one launch
  scgm_k<<<dim3(296), blk, 0, stream>>>(qkvfe, Sc, Gm);

  // per-edge: softmax + colsum@V (S1) + st2 via MFMA
  edge_finish<<<dim3(B * E), blk, 0, stream>>>(Sc, Gm, qkvfe, S1, eS);
  fe_k<<<dim3(2304), blk, 0, stream>>>(S1, eS, mask, fe);

  // two GNN layers
  for (int L = 0; L < 2; ++L) {
    const unsigned short* ABUVt = L ? ABUVt1 : ABUVt0;
    const unsigned short* wet   = L ? wet1 : wet0;
    {
      GJobs js{};
      js.j[0] = {f_v, ABUVt, nullptr, ABUV, nullptr, B * N, 2048, C, C, C, 2048, 0, 2};
      js.j[1] = {fe,  wet,   nullptr, EW,   nullptr, B * E, C,    C, C, C, C,    0, 18};
      js.ends[0] = 64; js.ends[1] = 208; js.ends[2] = 208; js.n = 2;
      gemm_jobs<<<dim3(208), blk, 0, stream>>>(js);
    }
    agg_stats<<<dim3(E), blk, 0, stream>>>(ABUV, EW, mu_e, rs_e);
    edmsg_k<<<dim3(B * N, 2), blk, 0, stream>>>(fe, ABUV, EW, mu_e, rs_e, pre, nps, npq);
    if (L == 0)
      xv_update<<<dim3((B * N * C + 255) / 256), blk, 0, stream>>>(f_v, pre, nps, npq);
  }

  out_k<<<dim3(B * N + B * E), blk, 0, stream>>>(f_v, pre, nps, npq, sc, fe, efc_w, efc_b, out);
}

// Round 11
// 213.707 us; speedup vs baseline: 1.0832x; 1.0335x over previous
//
#include <hip/hip_runtime.h>
#include <math.h>

namespace {

constexpr int B = 8, D = 49, C = 512, N = 12, H = 256, E = 144;
constexpr int M_BD  = B * D;        // 392
constexpr int M_BND = B * N * D;    // 4704
constexpr float BN_EPS = 1e-5f;
constexpr float ATT_SCALE = 0.0625f; // (C/2)^-0.5

typedef __attribute__((ext_vector_type(4))) float  floatx4;
typedef __attribute__((ext_vector_type(8))) short  shortx8;

__device__ inline unsigned short f2bf(float f) {
  unsigned u = __float_as_uint(f);
  return (unsigned short)((u + 0x7fffu + ((u >> 16) & 1u)) >> 16);
}
__device__ inline float bf2f(unsigned short u) {
  return __uint_as_float(((unsigned)u) << 16);
}

__device__ inline void gload16(const unsigned short* g, unsigned short* l) {
  __builtin_amdgcn_global_load_lds(
      (const __attribute__((address_space(1))) void*)g,
      (__attribute__((address_space(3))) void*)l, 16, 0, 0);
}

// ------- tcast (z<28): fp32 [512][Nn] -> bf16 [Nn][512]; z==28: castrow/bias/b2 -------
struct TCJobs {
  const float* src[28];
  unsigned short* dst[28];
  int nn[28];
};

__global__ __launch_bounds__(256)
void tcast_k(TCJobs jobs,
             const float* __restrict__ x, unsigned short* __restrict__ xb,
             const float* __restrict__ awv, unsigned short* __restrict__ armwvb,
             const float* __restrict__ bk, const float* __restrict__ bv,
             const float* __restrict__ bq2, const float* __restrict__ bk2,
             const float* __restrict__ arm_bv, const float* __restrict__ epw,
             const float* __restrict__ epb,
             float* __restrict__ kvbias, float* __restrict__ qkvbias)
{
  const int z = blockIdx.z;
  const int tid = threadIdx.x;
  if (z == 28) {
    int idx = (blockIdx.y * 16 + blockIdx.x) * 256 + tid;
    const int n1 = M_BD * C / 8;            // 25088
    const int n2 = n1 + C * C / 8;          // 57856
    if (idx < n1) {
      int i8 = idx * 8;
      float4 a = *reinterpret_cast<const float4*>(x + i8);
      float4 b = *reinterpret_cast<const float4*>(x + i8 + 4);
      shortx8 o;
      o[0]=(short)f2bf(a.x); o[1]=(short)f2bf(a.y); o[2]=(short)f2bf(a.z); o[3]=(short)f2bf(a.w);
      o[4]=(short)f2bf(b.x); o[5]=(short)f2bf(b.y); o[6]=(short)f2bf(b.z); o[7]=(short)f2bf(b.w);
      *reinterpret_cast<shortx8*>(xb + i8) = o;
    } else if (idx < n2) {
      int i8 = (idx - n1) * 8;
      float4 a = *reinterpret_cast<const float4*>(awv + i8);
      float4 b = *reinterpret_cast<const float4*>(awv + i8 + 4);
      shortx8 o;
      o[0]=(short)f2bf(a.x); o[1]=(short)f2bf(a.y); o[2]=(short)f2bf(a.z); o[3]=(short)f2bf(a.w);
      o[4]=(short)f2bf(b.x); o[5]=(short)f2bf(b.y); o[6]=(short)f2bf(b.z); o[7]=(short)f2bf(b.w);
      *reinterpret_cast<shortx8*>(armwvb + i8) = o;
    } else if (idx >= 58112 && idx < 58624) {
      int c = idx - 58112;
      float s = epb[c];
      for (int k = 0; k < C; ++k) s = fmaf(arm_bv[k], epw[k * C + c], s);
      qkvbias[512 + c] = s;
    }
    if (idx < 256) { kvbias[idx] = bk[idx]; qkvbias[idx] = bq2[idx]; qkvbias[256 + idx] = bk2[idx]; }
    if (idx < 512) kvbias[256 + idx] = bv[idx];
    return;
  }
  const float* src = jobs.src[z];
  unsigned short* dst = jobs.dst[z];
  const int Nn = jobs.nn[z];
  const int tx = blockIdx.x, ty = blockIdx.y;
  if (tx * 32 >= Nn) return;
  __shared__ float t[32][33];
  const int lr = tid >> 5, lc = tid & 31;
#pragma unroll
  for (int p = 0; p < 4; ++p) {
    int k = ty * 32 + p * 8 + lr;
    t[p * 8 + lr][lc] = src[(long long)k * Nn + tx * 32 + lc];
  }
  __syncthreads();
#pragma unroll
  for (int p = 0; p < 4; ++p) {
    int n = tx * 32 + p * 8 + lr;
    dst[(long long)n * 512 + ty * 32 + lc] = f2bf(t[lc][p * 8 + lr]);
  }
}

// ---------------- 64x64-tile bf16 MFMA GEMM body ----------------
__device__ __forceinline__
void gemm64_body(const void* __restrict__ Ain, const unsigned short* __restrict__ Bt,
                 const float* __restrict__ bp, float* __restrict__ co,
                 unsigned short* __restrict__ cb,
                 int M, int Nn, int K, int lda, int ldb, int ldc, int abf,
                 int bx, int by)
{
  const float* Af = abf ? nullptr : (const float*)Ain;
  const unsigned short* Ab = abf ? (const unsigned short*)Ain : nullptr;

  __shared__ short As[64 * 72];
  __shared__ short Bs[64 * 72];

  const int tid = threadIdx.x;
  const int row0 = bx * 64, col0 = by * 64;
  const int wid = tid >> 6, lane = tid & 63;
  const int wr = wid >> 1, wc = wid & 1;
  const int lr = lane & 15, lg = lane >> 4;

  floatx4 acc00 = {0.f,0.f,0.f,0.f}, acc01 = {0.f,0.f,0.f,0.f};
  floatx4 acc10 = {0.f,0.f,0.f,0.f}, acc11 = {0.f,0.f,0.f,0.f};

  const int r = tid >> 2, seg = tid & 3;
  const int gr = row0 + r, gn = col0 + r;
  short* aw = &As[r * 72 + seg * 16];
  short* bw = &Bs[r * 72 + seg * 16];
  const shortx8 zz = {0,0,0,0,0,0,0,0};

  for (int k0 = 0; k0 < K; k0 += 64) {
    shortx8 w0, w1;
    if (gr < M) {
      if (abf) {
        const shortx8* ap = reinterpret_cast<const shortx8*>(Ab + (long long)gr * lda + seg * 16 + k0);
        w0 = ap[0]; w1 = ap[1];
      } else {
        const float4* ap = reinterpret_cast<const float4*>(Af + (long long)gr * lda + seg * 16 + k0);
        float4 fa0 = ap[0], fa1 = ap[1], fa2 = ap[2], fa3 = ap[3];
        w0[0]=(short)f2bf(fa0.x); w0[1]=(short)f2bf(fa0.y); w0[2]=(short)f2bf(fa0.z); w0[3]=(short)f2bf(fa0.w);
        w0[4]=(short)f2bf(fa1.x); w0[5]=(short)f2bf(fa1.y); w0[6]=(short)f2bf(fa1.z); w0[7]=(short)f2bf(fa1.w);
        w1[0]=(short)f2bf(fa2.x); w1[1]=(short)f2bf(fa2.y); w1[2]=(short)f2bf(fa2.z); w1[3]=(short)f2bf(fa2.w);
        w1[4]=(short)f2bf(fa3.x); w1[5]=(short)f2bf(fa3.y); w1[6]=(short)f2bf(fa3.z); w1[7]=(short)f2bf(fa3.w);
      }
    } else { w0 = zz; w1 = zz; }
    const shortx8* bp8 = reinterpret_cast<const shortx8*>(Bt + (long long)gn * ldb + seg * 16 + k0);
    shortx8 b0v = bp8[0];
    shortx8 b1v = bp8[1];

    __syncthreads();
    *reinterpret_cast<shortx8*>(aw)     = w0;
    *reinterpret_cast<shortx8*>(aw + 8) = w1;
    *reinterpret_cast<shortx8*>(bw)     = b0v;
    *reinterpret_cast<shortx8*>(bw + 8) = b1v;
    __syncthreads();

#pragma unroll
    for (int kt = 0; kt < 2; ++kt) {
      shortx8 a0 = *reinterpret_cast<const shortx8*>(&As[(wr*32      + lr) * 72 + kt*32 + lg*8]);
      shortx8 a1 = *reinterpret_cast<const shortx8*>(&As[(wr*32 + 16 + lr) * 72 + kt*32 + lg*8]);
      shortx8 bb0 = *reinterpret_cast<const shortx8*>(&Bs[(wc*32      + lr) * 72 + kt*32 + lg*8]);
      shortx8 bb1 = *reinterpret_cast<const shortx8*>(&Bs[(wc*32 + 16 + lr) * 72 + kt*32 + lg*8]);
      acc00 = __builtin_amdgcn_mfma_f32_16x16x32_bf16(a0, bb0, acc00, 0, 0, 0);
      acc01 = __builtin_amdgcn_mfma_f32_16x16x32_bf16(a0, bb1, acc01, 0, 0, 0);
      acc10 = __builtin_amdgcn_mfma_f32_16x16x32_bf16(a1, bb0, acc10, 0, 0, 0);
      acc11 = __builtin_amdgcn_mfma_f32_16x16x32_bf16(a1, bb1, acc11, 0, 0, 0);
    }
  }

  const int colA = col0 + wc * 32 + lr;
  const int colB = colA + 16;
  const bool okA = colA < Nn, okB = colB < Nn;
  const float biasA = (bp && okA) ? bp[colA] : 0.f;
  const float biasB = (bp && okB) ? bp[colB] : 0.f;
  const int rb0 = row0 + wr * 32 + lg * 4;
  const int rb1 = rb0 + 16;
#pragma unroll
  for (int jj = 0; jj < 4; ++jj) {
    int ra = rb0 + jj, rb = rb1 + jj;
    float v00 = acc00[jj] + biasA, v01 = acc01[jj] + biasB;
    float v10 = acc10[jj] + biasA, v11 = acc11[jj] + biasB;
    if (ra < M) {
      if (co) { if (okA) co[(long long)ra * ldc + colA] = v00;
                if (okB) co[(long long)ra * ldc + colB] = v01; }
      if (cb) { if (okA) cb[(long long)ra * ldc + colA] = f2bf(v00);
                if (okB) cb[(long long)ra * ldc + colB] = f2bf(v01); }
    }
    if (rb < M) {
      if (co) { if (okA) co[(long long)rb * ldc + colA] = v10;
                if (okB) co[(long long)rb * ldc + colB] = v11; }
      if (cb) { if (okA) cb[(long long)rb * ldc + colA] = f2bf(v10);
                if (okB) cb[(long long)rb * ldc + colB] = f2bf(v11); }
    }
  }
}

// ---------------- z-batched 64² GEMM ----------------
__global__ __launch_bounds__(256)
void gemm_mfma(const void* __restrict__ Ain, const unsigned short* __restrict__ Bt,
               const float* __restrict__ bias, float* __restrict__ Co,
               unsigned short* __restrict__ Cb,
               int M, int Nn, int K, int lda, int ldb, int ldc, int abf,
               long long sA, long long sB, long long sBias, long long sC)
{
  const int z = blockIdx.z;
  const void* A = abf ? (const void*)((const unsigned short*)Ain + z * sA)
                      : (const void*)((const float*)Ain + z * sA);
  gemm64_body(A, Bt + z * sB, bias ? bias + z * sBias : nullptr,
              Co ? Co + z * sC : nullptr, Cb ? Cb + z * sC : nullptr,
              M, Nn, K, lda, ldb, ldc, abf, blockIdx.x, blockIdx.y);
}

// ---------------- multi-job 64² GEMM ----------------
struct GJob {
  const void* A; const unsigned short* B; const float* bias;
  float* Co; unsigned short* Cb;
  int M, Nn, K, lda, ldb, ldc, abf, tx;
};
struct GJobs { GJob j[3]; int ends[3]; int n; };

__global__ __launch_bounds__(256)
void gemm_jobs(GJobs js)
{
  const int bid = blockIdx.x;
#pragma unroll
  for (int q = 0; q < 3; ++q) {
    if (q < js.n && bid < js.ends[q]) {
      int start = q ? js.ends[q - 1] : 0;
      int local = bid - start;
      const GJob& J = js.j[q];
      gemm64_body(J.A, J.B, J.bias, J.Co, J.Cb,
                  J.M, J.Nn, J.K, J.lda, J.ldb, J.ldc, J.abf,
                  local % J.tx, local / J.tx);
      return;
    }
  }
}

// ------- 128²-tile GEMM body, global_load_lds staging; optional BN-stat partials -------
__device__ __forceinline__
void g128_body(const unsigned short* __restrict__ Ab, const unsigned short* __restrict__ Bt,
               const float* __restrict__ bp, float* __restrict__ co,
               unsigned short* __restrict__ cb, float* __restrict__ psb, float* __restrict__ pqb,
               int M, int Nn, int K, int lda, int ldb, int ldc, int bx, int by)
{
  __shared__ unsigned short As[128 * 64];
  __shared__ unsigned short Bs[128 * 64];

  const int tid = threadIdx.x;
  const int row0 = bx * 128, col0 = by * 128;
  const int wid = tid >> 6, lane = tid & 63;
  const int wr = wid >> 1, wc = wid & 1;
  const int lr = lane & 15, lg = lane >> 4;

  floatx4 acc[4][4];
#pragma unroll
  for (int mf = 0; mf < 4; ++mf)
#pragma unroll
    for (int nf = 0; nf < 4; ++nf) acc[mf][nf] = floatx4{0.f,0.f,0.f,0.f};

  const int rsub = tid >> 3;
  const int csub = (tid & 7) * 8;

  for (int k0 = 0; k0 < K; k0 += 64) {
    __syncthreads();
#pragma unroll
    for (int it = 0; it < 4; ++it) {
      int r = it * 32 + rsub;
      gload16(Ab + (long long)(row0 + r) * lda + k0 + csub, As + it * 2048 + tid * 8);
      gload16(Bt + (long long)(col0 + r) * ldb + k0 + csub, Bs + it * 2048 + tid * 8);
    }
    __syncthreads();

#pragma unroll
    for (int kt = 0; kt < 2; ++kt) {
      shortx8 af[4], bf[4];
#pragma unroll
      for (int mf = 0; mf < 4; ++mf)
        af[mf] = *reinterpret_cast<const shortx8*>(&As[(wr*64 + mf*16 + lr) * 64 + kt*32 + lg*8]);
#pragma unroll
      for (int nf = 0; nf < 4; ++nf)
        bf[nf] = *reinterpret_cast<const shortx8*>(&Bs[(wc*64 + nf*16 + lr) * 64 + kt*32 + lg*8]);
#pragma unroll
      for (int mf = 0; mf < 4; ++mf)
#pragma unroll
        for (int nf = 0; nf < 4; ++nf)
          acc[mf][nf] = __builtin_amdgcn_mfma_f32_16x16x32_bf16(af[mf], bf[nf], acc[mf][nf], 0, 0, 0);
    }
  }

#pragma unroll
  for (int nf = 0; nf < 4; ++nf) {
    const int col = col0 + wc * 64 + nf * 16 + lr;
    if (col >= Nn) continue;
    const float bv = bp ? bp[col] : 0.f;
#pragma unroll
    for (int mf = 0; mf < 4; ++mf) {
      const int rbase = row0 + wr * 64 + mf * 16 + lg * 4;
#pragma unroll
      for (int jj = 0; jj < 4; ++jj) {
        int row = rbase + jj;
        if (row >= M) continue;
        float v = acc[mf][nf][jj] + bv;
        if (co) co[(long long)row * ldc + col] = v;
        if (cb) cb[(long long)row * ldc + col] = f2bf(v);
      }
    }
  }

  if (psb) {
    __syncthreads();
    float* sb = (float*)As;
    sb[tid] = 0.f;
    __syncthreads();
#pragma unroll
    for (int nf = 0; nf < 4; ++nf) {
      const int lcol = wc * 64 + nf * 16 + lr;
      const int col = col0 + lcol;
      float s = 0.f, q = 0.f;
      if (col < Nn) {
        const float bv = bp ? bp[col] : 0.f;
#pragma unroll
        for (int mf = 0; mf < 4; ++mf) {
          const int rbase = row0 + wr * 64 + mf * 16 + lg * 4;
#pragma unroll
          for (int jj = 0; jj < 4; ++jj) {
            if (rbase + jj < M) { float v = acc[mf][nf][jj] + bv; s += v; q += v * v; }
          }
        }
      }
      atomicAdd(&sb[lcol], s);
      atomicAdd(&sb[128 + lcol], q);
    }
    __syncthreads();
    if (tid < 128) {
      psb[col0 + tid] = sb[tid];
      pqb[col0 + tid] = sb[128 + tid];
    }
  }
}

__global__ __launch_bounds__(256)
void gemm128g(const unsigned short* __restrict__ Ab, const unsigned short* __restrict__ Bt,
              const float* __restrict__ bias, float* __restrict__ Co,
              unsigned short* __restrict__ Cb, float* __restrict__ ps, float* __restrict__ pq,
              int M, int Nn, int K, int lda, int ldb, int ldc,
              long long sA, long long sB, long long sBias, long long sC)
{
  const int z = blockIdx.z;
  long long so = ((long long)blockIdx.x * gridDim.z + z) * ldc;
  g128_body(Ab + z * sA, Bt + z * sB, bias ? bias + z * sBias : nullptr,
            Co ? Co + z * sC : nullptr, Cb ? Cb + z * sC : nullptr,
            ps ? ps + so : nullptr, pq ? pq + so : nullptr,
            M, Nn, K, lda, ldb, ldc, blockIdx.x, blockIdx.y);
}

// ---------------- Sc (128² body) + Gm (64² body) in one launch ----------------
__global__ __launch_bounds__(256)
void scgm_k(const unsigned short* __restrict__ qkvfe, float* __restrict__ Sc,
            float* __restrict__ Gm)
{
  const int bid = blockIdx.x;
  if (bid < 200) {
    int z = bid / 25, rem = bid % 25;
    g128_body(qkvfe + (long long)z * 588 * 1024, qkvfe + 256 + (long long)z * 588 * 1024,
              nullptr, Sc + (long long)z * 588 * 588, nullptr, nullptr, nullptr,
              588, 588, H, 1024, 1024, 588, rem % 5, rem / 5);
  } else {
    int z = bid - 200;
    const unsigned short* vp = qkvfe + 512 + (long long)z * 49 * 1024;
    gemm64_body(vp, vp, nullptr, Gm + (long long)z * 2401, nullptr,
                D, D, C, 1024, 1024, D, 1, 0, 0);
  }
}

// ------- GNN layer GEMMs: blocks 0..35 EW (128² gload), 36..99 ABUV (64²) -------
__global__ __launch_bounds__(256)
void gnn_gemm_k(const unsigned short* __restrict__ feb, const unsigned short* __restrict__ wet,
                float* __restrict__ EW, const float* __restrict__ fv,
                const unsigned short* __restrict__ ABUVt, float* __restrict__ ABUV)
{
  const int bid = blockIdx.x;
  if (bid < 36) {
    g128_body(feb, wet, nullptr, EW, nullptr, nullptr, nullptr,
              B * E, C, C, C, C, C, bid % 9, bid / 9);
  } else {
    int local = bid - 36;
    gemm64_body(fv, ABUVt, nullptr, ABUV, nullptr,
                B * N, 2048, C, C, C, 2048, 0, local % 2, local / 2);
  }
}

// ------- f_u = relu(norm(h_bf16)) -> bf16, f_v = mean_d f_u (4-slice stats fold) -------
__global__ __launch_bounds__(256)
void fu_fv(const unsigned short* __restrict__ hb, const float* __restrict__ ps,
           const float* __restrict__ pq, unsigned short* __restrict__ fub,
           float* __restrict__ fv)
{
  const int bid = blockIdx.x;
  const int b = bid / N, n = bid % N;
  const int c = blockIdx.y * 256 + threadIdx.x;
  const int idx = n * C + c;
  float s = 0.f, q = 0.f;
#pragma unroll
  for (int sl = 0; sl < 4; ++sl) { s += ps[sl * (N * C) + idx]; q += pq[sl * (N * C) + idx]; }
  float m = s / (float)M_BD;
  float rv = rsqrtf(q / (float)M_BD - m * m + BN_EPS);
  float acc = 0.f;
  for (int d = 0; d < D; ++d) {
    float v = bf2f(hb[((long long)n * M_BD + b * D + d) * C + c]);
    v = fmaxf((v - m) * rv, 0.f);
    fub[((long long)bid * D + d) * C + c] = f2bf(v);
    acc += v;
  }
  fv[(long long)bid * C + c] = acc * (1.0f / (float)D);
}

// -- fused: fam softmax (0..18) + vx transpose (19..82) + cosine mask (83..90) --
__global__ __launch_bounds__(256)
void softvxt_k(const float* __restrict__ Sf, unsigned short* __restrict__ Ppb,
               const unsigned short* __restrict__ kvx, unsigned short* __restrict__ vxtb,
               const float* __restrict__ fv, float* __restrict__ maskp)
{
  const int tid = threadIdx.x;
  if (blockIdx.x < 19) {
    int row = blockIdx.x * 256 + tid;
    if (row >= M_BND) return;
    const float* p = Sf + (long long)row * 49;
    float v[49];
    float m = -1e30f;
#pragma unroll
    for (int j = 0; j < 49; ++j) { v[j] = p[j] * ATT_SCALE; m = fmaxf(m, v[j]); }
    float s = 0.f;
#pragma unroll
    for (int j = 0; j < 49; ++j) { v[j] = __expf(v[j] - m); s += v[j]; }
    float inv = 1.f / s;
    unsigned short* o = Ppb + (long long)row * 64;
#pragma unroll
    for (int j = 0; j < 49; ++j) o[j] = f2bf(v[j] * inv);
#pragma unroll
    for (int j = 49; j < 64; ++j) o[j] = 0;
    return;
  }
  if (blockIdx.x < 83) {
    const int i = blockIdx.x - 19;
    const int b = i >> 3, cc = i & 7;
    __shared__ unsigned short t[49][65];
    for (int idx = tid; idx < 49 * 64; idx += 256) {
      int rr = idx >> 6, k = idx & 63;
      t[rr][k] = kvx[(long long)(b * 49 + rr) * 768 + 256 + cc * 64 + k];
    }
    __syncthreads();
    for (int idx = tid; idx < 64 * 64; idx += 256) {
      int n = idx >> 6, kk = idx & 63;
      vxtb[((long long)b * 512 + cc * 64 + n) * 64 + kk] = (kk < 49) ? t[kk][n] : (unsigned short)0;
    }
    return;
  }
  const int b = blockIdx.x - 83;
  __shared__ float fl[N][C];
  __shared__ float adj[N][N];
  __shared__ float nrm[N];
  __shared__ float dis[N];
  for (int idx = tid; idx < N * C; idx += 256)
    fl[idx / C][idx % C] = fv[(long long)b * N * C + idx];
  __syncthreads();
  if (tid < N * N) {
    int i = tid / N, j = tid % N;
    float s = 0.f;
    for (int k = 0; k < C; ++k) s += fl[i][k] * fl[j][k];
    adj[i][j] = s;
  }
  __syncthreads();
  if (tid < N) nrm[tid] = fmaxf(sqrtf(adj[tid][tid]), 1e-12f);
  __syncthreads();
  if (tid < N * N) {
    int i = tid / N, j = tid % N;
    adj[i][j] = adj[i][j] / (nrm[i] * nrm[j]);
  }
  __syncthreads();
  if (tid < N) {
    float s = 0.f;
    for (int j = 0; j < N; ++j) s += adj[tid][j];
    dis[tid] = rsqrtf(s);
  }
  __syncthreads();
  if (tid < N * N) {
    int i = tid / N, j = tid % N;
    maskp[b * E + tid] = adj[i][j] * dis[i] * dis[j];
  }
}

// ------- edge finish: softmax + colsum@V (S1, 2-wide) + st2 = <A^T A, G> via MFMA -------
__global__ __launch_bounds__(256)
void edge_finish(const float* __restrict__ Sc, const float* __restrict__ G,
                 const unsigned short* __restrict__ qkvfe,
                 float* __restrict__ S1, float* __restrict__ eS)
{
  const int bid = blockIdx.x;           // b*E + e
  const int b = bid / E, e = bid % E;
  const int i = e / N, j = e % N;
  const float* Scb = Sc + (long long)b * 588 * 588 + (long long)(j * 49) * 588 + i * 49;
  const float* Gp  = G + (long long)(b * N + i) * 2401;
  const unsigned short* Vp = qkvfe + (long long)(b * N + i) * D * 1024 + 512;

  __shared__ float aT[49][53];          // aT[dj][di] = probs[di][dj]
  __shared__ float g[49][53];
  __shared__ unsigned short abT[64][72];
  __shared__ float ws[52];
  __shared__ float r0[4], r1[4];
  const int tid = threadIdx.x;
  const int wid = tid >> 6, lane = tid & 63;
  const int lr = lane & 15, lg = lane >> 4;

  for (int idx = tid; idx < 49 * 49; idx += 256) {
    int di = idx / 49, dj = idx - di * 49;
    aT[dj][di] = Scb[di * 588 + dj] * ATT_SCALE;
    g[di][dj] = Gp[idx];
  }
  __syncthreads();
  if (tid < D) {
    float m = -1e30f;
    for (int jj = 0; jj < D; ++jj) m = fmaxf(m, aT[jj][tid]);
    float s = 0.f;
    for (int jj = 0; jj < D; ++jj) { float ev = __expf(aT[jj][tid] - m); aT[jj][tid] = ev; s += ev; }
    float inv = 1.f / s;
    for (int jj = 0; jj < D; ++jj) aT[jj][tid] *= inv;
  }
  __syncthreads();
  for (int idx = tid; idx < 64 * 64; idx += 256) {
    int dj = idx >> 6, di = idx & 63;
    float v = (dj < D && di < D) ? aT[dj][di] : 0.f;
    abT[dj][di] = f2bf(v);
  }
  if (tid < D) {
    float s = 0.f;
    for (int di = 0; di < D; ++di) s += aT[tid][di];
    ws[tid] = s;
  }
  __syncthreads();

  floatx4 acc[4];
#pragma unroll
  for (int tk = 0; tk < 4; ++tk) acc[tk] = floatx4{0.f,0.f,0.f,0.f};
  shortx8 af0 = *reinterpret_cast<const shortx8*>(&abT[wid * 16 + lr][lg * 8]);
  shortx8 af1 = *reinterpret_cast<const shortx8*>(&abT[wid * 16 + lr][32 + lg * 8]);
#pragma unroll
  for (int tk = 0; tk < 4; ++tk) {
    shortx8 bf0v = *reinterpret_cast<const shortx8*>(&abT[tk * 16 + lr][lg * 8]);
    shortx8 bf1v = *reinterpret_cast<const shortx8*>(&abT[tk * 16 + lr][32 + lg * 8]);
    acc[tk] = __builtin_amdgcn_mfma_f32_16x16x32_bf16(af0, bf0v, acc[tk], 0, 0, 0);
    acc[tk] = __builtin_amdgcn_mfma_f32_16x16x32_bf16(af1, bf1v, acc[tk], 0, 0, 0);
  }
  float st2 = 0.f;
#pragma unroll
  for (int tk = 0; tk < 4; ++tk) {
    int kcol = tk * 16 + lr;
#pragma unroll
    for (int rg = 0; rg < 4; ++rg) {
      int jrow = wid * 16 + lg * 4 + rg;
      if (jrow < D && kcol < D) st2 = fmaf(acc[tk][rg], g[jrow][kcol], st2);
    }
  }

  // S1 = colsum(A) @ V  — 2 bf16 per lane per row
  const unsigned* Vp32 = reinterpret_cast<const unsigned*>(Vp);
  float s1a = 0.f, s1b = 0.f;
  for (int dk = 0; dk < D; ++dk) {
    unsigned u = Vp32[dk * 512 + tid];
    float w = ws[dk];
    s1a = fmaf(w, bf2f((unsigned short)(u & 0xffffu)), s1a);
    s1b = fmaf(w, bf2f((unsigned short)(u >> 16)), s1b);
  }
  S1[(long long)bid * C + 2 * tid]     = s1a;
  S1[(long long)bid * C + 2 * tid + 1] = s1b;
  float st = s1a + s1b;

  for (int off = 32; off; off >>= 1) { st += __shfl_down(st, off); st2 += __shfl_down(st2, off); }
  if (lane == 0) { r0[wid] = st; r1[wid] = st2; }
  __syncthreads();
  if (tid == 0) {
    eS[bid * 2 + 0] = r0[0] + r0[1] + r0[2] + r0[3];
    eS[bid * 2 + 1] = r1[0] + r1[1] + r1[2] + r1[3];
  }
}

// ------- f_e = (S1/D - me)*rve * mask; also writes bf16 copy for GEMM A -------
__global__ __launch_bounds__(256)
void fe_k(const float* __restrict__ S1, const float* __restrict__ eS,
          const float* __restrict__ maskp, float* __restrict__ fe,
          unsigned short* __restrict__ feb)
{
  __shared__ float csh[3];
  long long idx0 = (long long)blockIdx.x * 256;
  long long be = idx0 / C;
  int e = (int)(be % E);
  if (threadIdx.x == 0) {
    float s = 0.f, q = 0.f;
    for (int b = 0; b < B; ++b) { s += eS[(b * E + e) * 2]; q += eS[(b * E + e) * 2 + 1]; }
    const float inv = 1.f / (float)(B * D * C);
    float m = s * inv;
    csh[0] = m;
    csh[1] = rsqrtf(q * inv - m * m + BN_EPS);
    csh[2] = maskp[be];
  }
  __syncthreads();
  long long idx = idx0 + threadIdx.x;
  float v = (S1[idx] * (1.0f / (float)D) - csh[0]) * csh[1] * csh[2];
  fe[idx] = v;
  feb[idx] = f2bf(v);
}

// ---------------- GNN: BN stats per e over agg = A[i]+B[j]+EW[e] ----------------
__global__ __launch_bounds__(256)
void agg_stats(const float* __restrict__ ABUV, const float* __restrict__ EW,
               float* __restrict__ mu_e, float* __restrict__ rs_e)
{
  const int e = blockIdx.x;
  const int i = e / N, j = e % N;
  const int tid = threadIdx.x;
  float s = 0.f, q = 0.f;
  for (int idx = tid; idx < B * C; idx += 256) {
    int b = idx >> 9, c = idx & 511;
    float v = ABUV[(long long)(b * N + i) * 2048 + c]
            + ABUV[(long long)(b * N + j) * 2048 + 512 + c]
            + EW[((long long)b * E + e) * C + c];
    s += v; q += v * v;
  }
  for (int off = 32; off; off >>= 1) { s += __shfl_down(s, off); q += __shfl_down(q, off); }
  __shared__ float r0[4], r1[4];
  int wid = tid >> 6, lane = tid & 63;
  if (lane == 0) { r0[wid] = s; r1[wid] = q; }
  __syncthreads();
  if (tid == 0) {
    float ss = r0[0] + r0[1] + r0[2] + r0[3];
    float qq = r1[0] + r1[1] + r1[2] + r1[3];
    float m = ss / (float)(B * C);
    mu_e[e] = m;
    rs_e[e] = rsqrtf(qq / (float)(B * C) - m * m + BN_EPS);
  }
}

// -- fused: ed update (+bf16 copy) + sigmoid/softmax msg + pre + node-BN partials --
__global__ __launch_bounds__(256)
void edmsg_k(float* __restrict__ fe, unsigned short* __restrict__ feb,
             const float* __restrict__ ABUV,
             const float* __restrict__ EW, const float* __restrict__ mu_e,
             const float* __restrict__ rs_e, float* __restrict__ pre,
             float* __restrict__ nps, float* __restrict__ npq)
{
  const int bid = blockIdx.x;
  const int b = bid / N, i = bid % N;
  const int tid = threadIdx.x;
  float ls = 0.f, lq = 0.f;
  for (int c = tid; c < C; c += 256) {
    float ai = ABUV[(long long)(b * N + i) * 2048 + c];
    float sv[N];
    float m = -1e30f;
#pragma unroll
    for (int jn = 0; jn < N; ++jn) {
      int e = i * N + jn;
      float v = ai + ABUV[(long long)(b * N + jn) * 2048 + 512 + c]
              + EW[((long long)b * E + e) * C + c];
      v = (v - mu_e[e]) * rs_e[e];
      long long fidx = ((long long)b * E + e) * C + c;
      float ed = fe[fidx] + fmaxf(v, 0.f);
      fe[fidx] = ed;
      feb[fidx] = f2bf(ed);
      float sg = 1.f / (1.f + __expf(-ed));
      sv[jn] = sg; m = fmaxf(m, sg);
    }
    float sum = 0.f;
#pragma unroll
    for (int jn = 0; jn < N; ++jn) { float ev = __expf(sv[jn] - m); sv[jn] = ev; sum += ev; }
    float acc = 0.f;
#pragma unroll
    for (int jn = 0; jn < N; ++jn)
      acc = fmaf(sv[jn], ABUV[(long long)(b * N + jn) * 2048 + 1536 + c], acc);
    acc /= (sum * (float)N);
    float pv = ABUV[(long long)bid * 2048 + 1024 + c] + acc;
    pre[(long long)bid * C + c] = pv;
    ls += pv; lq += pv * pv;
  }
  for (int off = 32; off; off >>= 1) { ls += __shfl_down(ls, off); lq += __shfl_down(lq, off); }
  __shared__ float r0[4], r1[4];
  int wid = tid >> 6, lane = tid & 63;
  if (lane == 0) { r0[wid] = ls; r1[wid] = lq; }
  __syncthreads();
  if (tid == 0) {
    nps[i * B + b] = r0[0] + r0[1] + r0[2] + r0[3];
    npq[i * B + b] = r1[0] + r1[1] + r1[2] + r1[3];
  }
}

__global__ void xv_update(float* __restrict__ xv, const float* __restrict__ pre,
                          const float* __restrict__ nps, const float* __restrict__ npq)
{
  long long idx = (long long)blockIdx.x * 256 + threadIdx.x;
  if (idx >= (long long)B * N * C) return;
  int i = (int)((idx / C) % N);
  float s = 0.f, q = 0.f;
#pragma unroll
  for (int bb = 0; bb < B; ++bb) { s += nps[i * B + bb]; q += npq[i * B + bb]; }
  float mu = s * (1.f / (float)(B * C));
  float rs = rsqrtf(q * (1.f / (float)(B * C)) - mu * mu + BN_EPS);
  float v = xv[idx] + (pre[idx] - mu) * rs;
  xv[idx] = fmaxf(v, 0.f);
}

// ------- outputs: blocks 0..95 cosine classifier; blocks 96.. cl_edge -------
__global__ __launch_bounds__(256)
void out_k(const float* __restrict__ xv, const float* __restrict__ sc,
           const float* __restrict__ ed, const float* __restrict__ w,
           const float* __restrict__ bias, float* __restrict__ out)
{
  const int bid = blockIdx.x;
  const int tid = threadIdx.x;
  int wid = tid >> 6, lane = tid & 63;
  if (bid < B * N) {
    const int b = bid / N, i = bid % N;
    float sxx = 0.f, sss = 0.f, sxs = 0.f;
    for (int c = tid; c < C; c += 256) {
      float xvv = xv[(long long)(b * N + i) * C + c];
      float scv = fmaxf(sc[i * C + c], 0.f);
      sxx += xvv * xvv; sss += scv * scv; sxs += xvv * scv;
    }
    for (int off = 32; off; off >>= 1) {
      sxx += __shfl_down(sxx, off);
      sss += __shfl_down(sss, off);
      sxs += __shfl_down(sxs, off);
    }
    __shared__ float r0[4], r1[4], r2[4];
    if (lane == 0) { r0[wid] = sxx; r1[wid] = sss; r2[wid] = sxs; }
    __syncthreads();
    if (tid == 0) {
      float a = r0[0] + r0[1] + r0[2] + r0[3];
      float s = r1[0] + r1[1] + r1[2] + r1[3];
      float p = r2[0] + r2[1] + r2[2] + r2[3];
      float nx = fmaxf(sqrtf(a), 1e-12f);
      float ns = fmaxf(sqrtf(s), 1e-12f);
      out[b * N + i] = p / (nx * ns);
    }
  } else {
    const int eb = bid - B * N;
    float a0 = 0, a1 = 0, a2 = 0, a3 = 0;
    for (int c = tid; c < C; c += 256) {
      float v = ed[(long long)eb * C + c];
      a0 = fmaf(v, w[c * 4 + 0], a0);
      a1 = fmaf(v, w[c * 4 + 1], a1);
      a2 = fmaf(v, w[c * 4 + 2], a2);
      a3 = fmaf(v, w[c * 4 + 3], a3);
    }
    for (int off = 32; off; off >>= 1) {
      a0 += __shfl_down(a0, off);
      a1 += __shfl_down(a1, off);
      a2 += __shfl_down(a2, off);
      a3 += __shfl_down(a3, off);
    }
    __shared__ float r[4][4];
    if (lane == 0) { r[wid][0] = a0; r[wid][1] = a1; r[wid][2] = a2; r[wid][3] = a3; }
    __syncthreads();
    if (tid < 4) {
      float s = r[0][tid] + r[1][tid] + r[2][tid] + r[3][tid];
      out[B * N + eb * 4 + tid] = s + bias[tid];
    }
  }
}

} // namespace

extern "C" void kernel_launch(void* const* d_in, const int* in_sizes, int n_in,
                              void* d_out, int out_size, void* d_ws, size_t ws_size,
                              hipStream_t stream)
{
  (void)in_sizes; (void)n_in; (void)out_size; (void)ws_size;
  const float* x      = (const float*)d_in[0];
  const float* Wc     = (const float*)d_in[1];
  const float* bc     = (const float*)d_in[2];
  const float* fam_wq = (const float*)d_in[3];
  const float* fam_bq = (const float*)d_in[4];
  const float* fam_wk = (const float*)d_in[5];
  const float* fam_bk = (const float*)d_in[6];
  const float* fam_wv = (const float*)d_in[7];
  const float* fam_bv = (const float*)d_in[8];
  const float* arm_wq = (const float*)d_in[9];
  const float* arm_bq = (const float*)d_in[10];
  const float* arm_wk = (const float*)d_in[11];
  const float* arm_bk = (const float*)d_in[12];
  const float* arm_wv = (const float*)d_in[13];
  const float* arm_bv = (const float*)d_in[14];
  const float* ep_w   = (const float*)d_in[15];
  const float* ep_b   = (const float*)d_in[16];
  const float* gw[10] = {
    (const float*)d_in[17], (const float*)d_in[18], (const float*)d_in[19],
    (const float*)d_in[20], (const float*)d_in[21],
    (const float*)d_in[22], (const float*)d_in[23], (const float*)d_in[24],
    (const float*)d_in[25], (const float*)d_in[26]};
  const float* sc     = (const float*)d_in[27];
  const float* efc_w  = (const float*)d_in[28];
  const float* efc_b  = (const float*)d_in[29];
  float* out = (float*)d_out;

  char* wsb = (char*)d_ws;
  size_t off = 0;
  auto allocf = [&](size_t n) { float* p = (float*)(wsb + off); off += ((n * 4 + 255) / 256) * 256; return p; };
  auto allocu = [&](size_t n) { unsigned short* p = (unsigned short*)(wsb + off); off += ((n * 2 + 255) / 256) * 256; return p; };

  float* Sc    = allocf(2766336);
  float* bnp_s = allocf(24576);            // 4 slices x N x C
  float* bnp_q = allocf(24576);
  float* f_v   = allocf(49152);
  float* Sf    = allocf(230496);           // 8*588*49
  float* Gm    = allocf(230496);           // 96*49*49
  float* S1    = allocf(589824);
  float* fe    = allocf(589824);
  float* EW    = allocf(589824);
  float* eS    = allocf(2304);
  float* mask  = allocf(1152);
  float* ABUV  = allocf(196608);
  float* pre   = allocf(49152);
  float* mu_e  = allocf(144);
  float* rs_e  = allocf(144);
  float* nps   = allocf(96);
  float* npq   = allocf(96);
  float* kvbias  = allocf(768);
  float* qkvbias = allocf(1024);           // [arm_bq|arm_bk|b2]

  unsigned short* Wct    = allocu(3145728);
  unsigned short* famqt  = allocu(131072);
  unsigned short* kvwt   = allocu(393216);   // [768][512]: fam_wk | fam_wv
  unsigned short* qkw2t  = allocu(524288);   // [1024][512]: arm_wq | arm_wk | W2^T
  unsigned short* epwt   = allocu(262144);
  unsigned short* armwvb = allocu(262144);   // arm_wv row-major bf16
  unsigned short* wet0   = allocu(262144);
  unsigned short* wet1   = allocu(262144);
  unsigned short* ABUVt0 = allocu(1048576);
  unsigned short* ABUVt1 = allocu(1048576);
  unsigned short* xb     = allocu(262144);   // [512][512] (rows padded for gload)
  unsigned short* hb     = allocu(2408448);  // h bf16 [12][392][512]
  unsigned short* fub    = allocu(2408448);
  unsigned short* q1b    = allocu(1204224);  // [4704][256]
  unsigned short* kxvx_b = allocu(350208);   // [456][768] (pad rows for B overread)
  unsigned short* Ppb    = allocu(301056);   // [4704][64]
  unsigned short* vxtb   = allocu(262144);   // [8][512][64]
  unsigned short* featb  = allocu(2424832);  // [4736][512] (rows padded for gload)
  unsigned short* qkvfe  = allocu(4915200);  // [4800][1024]: q|k|vfe (pad rows)
  unsigned short* feb    = allocu(589824);   // fe bf16 [1152][512] (1152 = 9*128 exact)

  dim3 blk(256);

  // -------- weight transpose+cast (28 jobs) + castrow/bias/b2 branch (z=28) --------
  TCJobs tj{};
  int jn = 0;
  for (int n = 0; n < 12; ++n) { tj.src[jn] = Wc + (size_t)n * C * C; tj.dst[jn] = Wct + (size_t)n * C * C; tj.nn[jn] = C; ++jn; }
  tj.src[jn] = fam_wq; tj.dst[jn] = famqt;             tj.nn[jn] = H; ++jn;
  tj.src[jn] = fam_wk; tj.dst[jn] = kvwt;              tj.nn[jn] = H; ++jn;
  tj.src[jn] = fam_wv; tj.dst[jn] = kvwt + 256 * 512;  tj.nn[jn] = C; ++jn;
  tj.src[jn] = arm_wq; tj.dst[jn] = qkw2t;             tj.nn[jn] = H; ++jn;
  tj.src[jn] = arm_wk; tj.dst[jn] = qkw2t + 256 * 512; tj.nn[jn] = H; ++jn;
  tj.src[jn] = ep_w;   tj.dst[jn] = epwt;              tj.nn[jn] = C; ++jn;
  tj.src[jn] = gw[2];  tj.dst[jn] = wet0;              tj.nn[jn] = C; ++jn;
  tj.src[jn] = gw[7];  tj.dst[jn] = wet1;              tj.nn[jn] = C; ++jn;
  tj.src[jn] = gw[0];  tj.dst[jn] = ABUVt0;               tj.nn[jn] = C; ++jn;
  tj.src[jn] = gw[1];  tj.dst[jn] = ABUVt0 + 1 * C * C;   tj.nn[jn] = C; ++jn;
  tj.src[jn] = gw[3];  tj.dst[jn] = ABUVt0 + 2 * C * C;   tj.nn[jn] = C; ++jn;
  tj.src[jn] = gw[4];  tj.dst[jn] = ABUVt0 + 3 * C * C;   tj.nn[jn] = C; ++jn;
  tj.src[jn] = gw[5];  tj.dst[jn] = ABUVt1;               tj.nn[jn] = C; ++jn;
  tj.src[jn] = gw[6];  tj.dst[jn] = ABUVt1 + 1 * C * C;   tj.nn[jn] = C; ++jn;
  tj.src[jn] = gw[8];  tj.dst[jn] = ABUVt1 + 2 * C * C;   tj.nn[jn] = C; ++jn;
  tj.src[jn] = gw[9];  tj.dst[jn] = ABUVt1 + 3 * C * C;   tj.nn[jn] = C; ++jn;
  tcast_k<<<dim3(16, 16, 29), blk, 0, stream>>>(tj, x, xb, arm_wv, armwvb,
      fam_bk, fam_bv, arm_bq, arm_bk, arm_bv, ep_w, ep_b, kvbias, qkvbias);

  // h[n] = x @ Wc[n] + bc[n]  (128² gload tiles, BN stats fused, bf16 out)
  gemm128g<<<dim3(4, 4, 12), blk, 0, stream>>>(xb, Wct, bc, nullptr, hb, bnp_s, bnp_q,
      M_BD, C, C, C, C, C, 0LL, (long long)C * C, (long long)C, (long long)M_BD * C);
  fu_fv<<<dim3(B * N, 2), blk, 0, stream>>>(hb, bnp_s, bnp_q, fub, f_v);

  // batched: q1 (fam q), kxvx (fam k|v), W2^T = ep_w^T @ arm_wv^T
  {
    GJobs js{};
    js.j[0] = {fub,  famqt,  fam_bq, nullptr, q1b,            M_BND, H,   C, C, C, H,   1, 74};
    js.j[1] = {xb,   kvwt,   kvbias, nullptr, kxvx_b,         M_BD,  768, C, C, C, 768, 1, 7};
    js.j[2] = {epwt, armwvb, nullptr, nullptr, qkw2t + 512 * 512, C,  C,   C, C, C, C,   1, 8};
    js.ends[0] = 296; js.ends[1] = 380; js.ends[2] = 444; js.n = 3;
    gemm_jobs<<<dim3(444), blk, 0, stream>>>(js);
  }
  // Sf[b] = q1[b] @ kx[b]^T  (588 x 49)
  gemm_mfma<<<dim3(10, 1, 8), blk, 0, stream>>>(q1b, kxvx_b, nullptr, Sf, nullptr,
      588, 49, H, H, 768, 49, 1, 588LL * 256, 49LL * 768, 0LL, 588LL * 49);
  softvxt_k<<<dim3(91), blk, 0, stream>>>(Sf, Ppb, kxvx_b, vxtb, f_v, mask);
  // feat[b] = P[b] @ vx[b]  (588 x 512, K=64)
  gemm_mfma<<<dim3(10, 8, 8), blk, 0, stream>>>(Ppb, vxtb, nullptr, nullptr, featb,
      588, C, 64, 64, 64, C, 1, 588LL * 64, 512LL * 64, 0LL, 588LL * 512);

  // merged arm q|k|vfe projection
  gemm128g<<<dim3(37, 8, 1), blk, 0, stream>>>(featb, qkw2t, qkvbias, nullptr, qkvfe,
      nullptr, nullptr, M_BND, 1024, C, C, C, 1024, 0, 0, 0, 0);

  // Sc[b] = qf[b] @ kf[b]^T (128² tiles) + G[node] = vfe vfe^T (64² tiles), one launch
  scgm_k<<<dim3(296), blk, 0, stream>>>(qkvfe, Sc, Gm);

  // per-edge: softmax + colsum@V (S1) + st2 via MFMA
  edge_finish<<<dim3(B * E), blk, 0, stream>>>(Sc, Gm, qkvfe, S1, eS);
  fe_k<<<dim3(2304), blk, 0, stream>>>(S1, eS, mask, fe, feb);

  // two GNN layers
  for (int L = 0; L < 2; ++L) {
    const unsigned short* ABUVt = L ? ABUVt1 : ABUVt0;
    const unsigned short* wet   = L ? wet1 : wet0;
    gnn_gemm_k<<<dim3(100), blk, 0, stream>>>(feb, wet, EW, f_v, ABUVt, ABUV);
    agg_stats<<<dim3(E), blk, 0, stream>>>(ABUV, EW, mu_e, rs_e);
    edmsg_k<<<dim3(B * N), blk, 0, stream>>>(fe, feb, ABUV, EW, mu_e, rs_e, pre, nps, npq);
    xv_update<<<dim3((B * N * C + 255) / 256), blk, 0, stream>>>(f_v, pre, nps, npq);
  }

  out_k<<<dim3(B * N + B * E), blk, 0, stream>>>(f_v, sc, fe, efc_w, efc_b, out);
}

// Round 12
// 209.556 us; speedup vs baseline: 1.1046x; 1.0198x over previous
//
#include <hip/hip_runtime.h>
#include <math.h>

namespace {

constexpr int B = 8, D = 49, C = 512, N = 12, H = 256, E = 144;
constexpr int M_BD  = B * D;        // 392
constexpr int M_BND = B * N * D;    // 4704
constexpr float BN_EPS = 1e-5f;
constexpr float ATT_SCALE = 0.0625f; // (C/2)^-0.5

typedef __attribute__((ext_vector_type(4))) float  floatx4;
typedef __attribute__((ext_vector_type(8))) short  shortx8;

__device__ inline unsigned short f2bf(float f) {
  unsigned u = __float_as_uint(f);
  return (unsigned short)((u + 0x7fffu + ((u >> 16) & 1u)) >> 16);
}
__device__ inline float bf2f(unsigned short u) {
  return __uint_as_float(((unsigned)u) << 16);
}

__device__ inline void gload16(const unsigned short* g, unsigned short* l) {
  __builtin_amdgcn_global_load_lds(
      (const __attribute__((address_space(1))) void*)g,
      (__attribute__((address_space(3))) void*)l, 16, 0, 0);
}

// ------- tcast (z<28): fp32 [512][Nn] -> bf16 [Nn][512]; z==28: castrow/bias/b2 -------
struct TCJobs {
  const float* src[28];
  unsigned short* dst[28];
  int nn[28];
};

__global__ __launch_bounds__(256)
void tcast_k(TCJobs jobs,
             const float* __restrict__ x, unsigned short* __restrict__ xb,
             const float* __restrict__ awv, unsigned short* __restrict__ armwvb,
             const float* __restrict__ bk, const float* __restrict__ bv,
             const float* __restrict__ bq2, const float* __restrict__ bk2,
             const float* __restrict__ arm_bv, const float* __restrict__ epw,
             const float* __restrict__ epb,
             float* __restrict__ kvbias, float* __restrict__ qkvbias)
{
  const int z = blockIdx.z;
  const int tid = threadIdx.x;
  if (z == 28) {
    int idx = (blockIdx.y * 16 + blockIdx.x) * 256 + tid;
    const int n1 = M_BD * C / 8;            // 25088
    const int n2 = n1 + C * C / 8;          // 57856
    if (idx < n1) {
      int i8 = idx * 8;
      float4 a = *reinterpret_cast<const float4*>(x + i8);
      float4 b = *reinterpret_cast<const float4*>(x + i8 + 4);
      shortx8 o;
      o[0]=(short)f2bf(a.x); o[1]=(short)f2bf(a.y); o[2]=(short)f2bf(a.z); o[3]=(short)f2bf(a.w);
      o[4]=(short)f2bf(b.x); o[5]=(short)f2bf(b.y); o[6]=(short)f2bf(b.z); o[7]=(short)f2bf(b.w);
      *reinterpret_cast<shortx8*>(xb + i8) = o;
    } else if (idx < n2) {
      int i8 = (idx - n1) * 8;
      float4 a = *reinterpret_cast<const float4*>(awv + i8);
      float4 b = *reinterpret_cast<const float4*>(awv + i8 + 4);
      shortx8 o;
      o[0]=(short)f2bf(a.x); o[1]=(short)f2bf(a.y); o[2]=(short)f2bf(a.z); o[3]=(short)f2bf(a.w);
      o[4]=(short)f2bf(b.x); o[5]=(short)f2bf(b.y); o[6]=(short)f2bf(b.z); o[7]=(short)f2bf(b.w);
      *reinterpret_cast<shortx8*>(armwvb + i8) = o;
    } else if (idx >= 58112 && idx < 58624) {
      int c = idx - 58112;
      float s = epb[c];
      for (int k = 0; k < C; ++k) s = fmaf(arm_bv[k], epw[k * C + c], s);
      qkvbias[512 + c] = s;
    }
    if (idx < 256) { kvbias[idx] = bk[idx]; qkvbias[idx] = bq2[idx]; qkvbias[256 + idx] = bk2[idx]; }
    if (idx < 512) kvbias[256 + idx] = bv[idx];
    return;
  }
  const float* src = jobs.src[z];
  unsigned short* dst = jobs.dst[z];
  const int Nn = jobs.nn[z];
  const int tx = blockIdx.x, ty = blockIdx.y;
  if (tx * 32 >= Nn) return;
  __shared__ float t[32][33];
  const int lr = tid >> 5, lc = tid & 31;
#pragma unroll
  for (int p = 0; p < 4; ++p) {
    int k = ty * 32 + p * 8 + lr;
    t[p * 8 + lr][lc] = src[(long long)k * Nn + tx * 32 + lc];
  }
  __syncthreads();
#pragma unroll
  for (int p = 0; p < 4; ++p) {
    int n = tx * 32 + p * 8 + lr;
    dst[(long long)n * 512 + ty * 32 + lc] = f2bf(t[lc][p * 8 + lr]);
  }
}

// ---------------- 64x64-tile bf16 MFMA GEMM body ----------------
__device__ __forceinline__
void gemm64_body(const void* __restrict__ Ain, const unsigned short* __restrict__ Bt,
                 const float* __restrict__ bp, float* __restrict__ co,
                 unsigned short* __restrict__ cb,
                 int M, int Nn, int K, int lda, int ldb, int ldc, int abf,
                 int bx, int by)
{
  const float* Af = abf ? nullptr : (const float*)Ain;
  const unsigned short* Ab = abf ? (const unsigned short*)Ain : nullptr;

  __shared__ short As[64 * 72];
  __shared__ short Bs[64 * 72];

  const int tid = threadIdx.x;
  const int row0 = bx * 64, col0 = by * 64;
  const int wid = tid >> 6, lane = tid & 63;
  const int wr = wid >> 1, wc = wid & 1;
  const int lr = lane & 15, lg = lane >> 4;

  floatx4 acc00 = {0.f,0.f,0.f,0.f}, acc01 = {0.f,0.f,0.f,0.f};
  floatx4 acc10 = {0.f,0.f,0.f,0.f}, acc11 = {0.f,0.f,0.f,0.f};

  const int r = tid >> 2, seg = tid & 3;
  const int gr = row0 + r, gn = col0 + r;
  short* aw = &As[r * 72 + seg * 16];
  short* bw = &Bs[r * 72 + seg * 16];
  const shortx8 zz = {0,0,0,0,0,0,0,0};

  for (int k0 = 0; k0 < K; k0 += 64) {
    shortx8 w0, w1;
    if (gr < M) {
      if (abf) {
        const shortx8* ap = reinterpret_cast<const shortx8*>(Ab + (long long)gr * lda + seg * 16 + k0);
        w0 = ap[0]; w1 = ap[1];
      } else {
        const float4* ap = reinterpret_cast<const float4*>(Af + (long long)gr * lda + seg * 16 + k0);
        float4 fa0 = ap[0], fa1 = ap[1], fa2 = ap[2], fa3 = ap[3];
        w0[0]=(short)f2bf(fa0.x); w0[1]=(short)f2bf(fa0.y); w0[2]=(short)f2bf(fa0.z); w0[3]=(short)f2bf(fa0.w);
        w0[4]=(short)f2bf(fa1.x); w0[5]=(short)f2bf(fa1.y); w0[6]=(short)f2bf(fa1.z); w0[7]=(short)f2bf(fa1.w);
        w1[0]=(short)f2bf(fa2.x); w1[1]=(short)f2bf(fa2.y); w1[2]=(short)f2bf(fa2.z); w1[3]=(short)f2bf(fa2.w);
        w1[4]=(short)f2bf(fa3.x); w1[5]=(short)f2bf(fa3.y); w1[6]=(short)f2bf(fa3.z); w1[7]=(short)f2bf(fa3.w);
      }
    } else { w0 = zz; w1 = zz; }
    const shortx8* bp8 = reinterpret_cast<const shortx8*>(Bt + (long long)gn * ldb + seg * 16 + k0);
    shortx8 b0v = bp8[0];
    shortx8 b1v = bp8[1];

    __syncthreads();
    *reinterpret_cast<shortx8*>(aw)     = w0;
    *reinterpret_cast<shortx8*>(aw + 8) = w1;
    *reinterpret_cast<shortx8*>(bw)     = b0v;
    *reinterpret_cast<shortx8*>(bw + 8) = b1v;
    __syncthreads();

#pragma unroll
    for (int kt = 0; kt < 2; ++kt) {
      shortx8 a0 = *reinterpret_cast<const shortx8*>(&As[(wr*32      + lr) * 72 + kt*32 + lg*8]);
      shortx8 a1 = *reinterpret_cast<const shortx8*>(&As[(wr*32 + 16 + lr) * 72 + kt*32 + lg*8]);
      shortx8 bb0 = *reinterpret_cast<const shortx8*>(&Bs[(wc*32      + lr) * 72 + kt*32 + lg*8]);
      shortx8 bb1 = *reinterpret_cast<const shortx8*>(&Bs[(wc*32 + 16 + lr) * 72 + kt*32 + lg*8]);
      acc00 = __builtin_amdgcn_mfma_f32_16x16x32_bf16(a0, bb0, acc00, 0, 0, 0);
      acc01 = __builtin_amdgcn_mfma_f32_16x16x32_bf16(a0, bb1, acc01, 0, 0, 0);
      acc10 = __builtin_amdgcn_mfma_f32_16x16x32_bf16(a1, bb0, acc10, 0, 0, 0);
      acc11 = __builtin_amdgcn_mfma_f32_16x16x32_bf16(a1, bb1, acc11, 0, 0, 0);
    }
  }

  const int colA = col0 + wc * 32 + lr;
  const int colB = colA + 16;
  const bool okA = colA < Nn, okB = colB < Nn;
  const float biasA = (bp && okA) ? bp[colA] : 0.f;
  const float biasB = (bp && okB) ? bp[colB] : 0.f;
  const int rb0 = row0 + wr * 32 + lg * 4;
  const int rb1 = rb0 + 16;
#pragma unroll
  for (int jj = 0; jj < 4; ++jj) {
    int ra = rb0 + jj, rb = rb1 + jj;
    float v00 = acc00[jj] + biasA, v01 = acc01[jj] + biasB;
    float v10 = acc10[jj] + biasA, v11 = acc11[jj] + biasB;
    if (ra < M) {
      if (co) { if (okA) co[(long long)ra * ldc + colA] = v00;
                if (okB) co[(long long)ra * ldc + colB] = v01; }
      if (cb) { if (okA) cb[(long long)ra * ldc + colA] = f2bf(v00);
                if (okB) cb[(long long)ra * ldc + colB] = f2bf(v01); }
    }
    if (rb < M) {
      if (co) { if (okA) co[(long long)rb * ldc + colA] = v10;
                if (okB) co[(long long)rb * ldc + colB] = v11; }
      if (cb) { if (okA) cb[(long long)rb * ldc + colA] = f2bf(v10);
                if (okB) cb[(long long)rb * ldc + colB] = f2bf(v11); }
    }
  }
}

// ---------------- z-batched 64² GEMM ----------------
__global__ __launch_bounds__(256)
void gemm_mfma(const void* __restrict__ Ain, const unsigned short* __restrict__ Bt,
               const float* __restrict__ bias, float* __restrict__ Co,
               unsigned short* __restrict__ Cb,
               int M, int Nn, int K, int lda, int ldb, int ldc, int abf,
               long long sA, long long sB, long long sBias, long long sC)
{
  const int z = blockIdx.z;
  const void* A = abf ? (const void*)((const unsigned short*)Ain + z * sA)
                      : (const void*)((const float*)Ain + z * sA);
  gemm64_body(A, Bt + z * sB, bias ? bias + z * sBias : nullptr,
              Co ? Co + z * sC : nullptr, Cb ? Cb + z * sC : nullptr,
              M, Nn, K, lda, ldb, ldc, abf, blockIdx.x, blockIdx.y);
}

// ------- 128²-tile GEMM body, global_load_lds staging; optional BN-stat partials -------
__device__ __forceinline__
void g128_body(const unsigned short* __restrict__ Ab, const unsigned short* __restrict__ Bt,
               const float* __restrict__ bp, float* __restrict__ co,
               unsigned short* __restrict__ cb, float* __restrict__ psb, float* __restrict__ pqb,
               int M, int Nn, int K, int lda, int ldb, int ldc, int bx, int by)
{
  __shared__ unsigned short As[128 * 64];
  __shared__ unsigned short Bs[128 * 64];

  const int tid = threadIdx.x;
  const int row0 = bx * 128, col0 = by * 128;
  const int wid = tid >> 6, lane = tid & 63;
  const int wr = wid >> 1, wc = wid & 1;
  const int lr = lane & 15, lg = lane >> 4;

  floatx4 acc[4][4];
#pragma unroll
  for (int mf = 0; mf < 4; ++mf)
#pragma unroll
    for (int nf = 0; nf < 4; ++nf) acc[mf][nf] = floatx4{0.f,0.f,0.f,0.f};

  const int rsub = tid >> 3;
  const int csub = (tid & 7) * 8;

  for (int k0 = 0; k0 < K; k0 += 64) {
    __syncthreads();
#pragma unroll
    for (int it = 0; it < 4; ++it) {
      int r = it * 32 + rsub;
      gload16(Ab + (long long)(row0 + r) * lda + k0 + csub, As + it * 2048 + tid * 8);
      gload16(Bt + (long long)(col0 + r) * ldb + k0 + csub, Bs + it * 2048 + tid * 8);
    }
    __syncthreads();

#pragma unroll
    for (int kt = 0; kt < 2; ++kt) {
      shortx8 af[4], bf[4];
#pragma unroll
      for (int mf = 0; mf < 4; ++mf)
        af[mf] = *reinterpret_cast<const shortx8*>(&As[(wr*64 + mf*16 + lr) * 64 + kt*32 + lg*8]);
#pragma unroll
      for (int nf = 0; nf < 4; ++nf)
        bf[nf] = *reinterpret_cast<const shortx8*>(&Bs[(wc*64 + nf*16 + lr) * 64 + kt*32 + lg*8]);
#pragma unroll
      for (int mf = 0; mf < 4; ++mf)
#pragma unroll
        for (int nf = 0; nf < 4; ++nf)
          acc[mf][nf] = __builtin_amdgcn_mfma_f32_16x16x32_bf16(af[mf], bf[nf], acc[mf][nf], 0, 0, 0);
    }
  }

#pragma unroll
  for (int nf = 0; nf < 4; ++nf) {
    const int col = col0 + wc * 64 + nf * 16 + lr;
    if (col >= Nn) continue;
    const float bv = bp ? bp[col] : 0.f;
#pragma unroll
    for (int mf = 0; mf < 4; ++mf) {
      const int rbase = row0 + wr * 64 + mf * 16 + lg * 4;
#pragma unroll
      for (int jj = 0; jj < 4; ++jj) {
        int row = rbase + jj;
        if (row >= M) continue;
        float v = acc[mf][nf][jj] + bv;
        if (co) co[(long long)row * ldc + col] = v;
        if (cb) cb[(long long)row * ldc + col] = f2bf(v);
      }
    }
  }

  if (psb) {
    __syncthreads();
    float* sb = (float*)As;
    sb[tid] = 0.f;
    __syncthreads();
#pragma unroll
    for (int nf = 0; nf < 4; ++nf) {
      const int lcol = wc * 64 + nf * 16 + lr;
      const int col = col0 + lcol;
      float s = 0.f, q = 0.f;
      if (col < Nn) {
        const float bv = bp ? bp[col] : 0.f;
#pragma unroll
        for (int mf = 0; mf < 4; ++mf) {
          const int rbase = row0 + wr * 64 + mf * 16 + lg * 4;
#pragma unroll
          for (int jj = 0; jj < 4; ++jj) {
            if (rbase + jj < M) { float v = acc[mf][nf][jj] + bv; s += v; q += v * v; }
          }
        }
      }
      atomicAdd(&sb[lcol], s);
      atomicAdd(&sb[128 + lcol], q);
    }
    __syncthreads();
    if (tid < 128) {
      psb[col0 + tid] = sb[tid];
      pqb[col0 + tid] = sb[128 + tid];
    }
  }
}

__global__ __launch_bounds__(256)
void gemm128g(const unsigned short* __restrict__ Ab, const unsigned short* __restrict__ Bt,
              const float* __restrict__ bias, float* __restrict__ Co,
              unsigned short* __restrict__ Cb, float* __restrict__ ps, float* __restrict__ pq,
              int M, int Nn, int K, int lda, int ldb, int ldc,
              long long sA, long long sB, long long sBias, long long sC)
{
  const int z = blockIdx.z;
  long long so = ((long long)blockIdx.x * gridDim.z + z) * ldc;
  g128_body(Ab + z * sA, Bt + z * sB, bias ? bias + z * sBias : nullptr,
            Co ? Co + z * sC : nullptr, Cb ? Cb + z * sC : nullptr,
            ps ? ps + so : nullptr, pq ? pq + so : nullptr,
            M, Nn, K, lda, ldb, ldc, blockIdx.x, blockIdx.y);
}

// ---- mega launch: h (blocks 0..191, 128² gload + BN stats) | fam k|v (192..275) | W2^T (276..339) ----
__global__ __launch_bounds__(256)
void proj1_k(const unsigned short* __restrict__ xb, const unsigned short* __restrict__ Wct,
             const float* __restrict__ bc, unsigned short* __restrict__ hb,
             float* __restrict__ ps, float* __restrict__ pq,
             const unsigned short* __restrict__ kvwt, const float* __restrict__ kvbias,
             unsigned short* __restrict__ kxvx_b,
             const unsigned short* __restrict__ epwt, const unsigned short* __restrict__ armwvb,
             unsigned short* __restrict__ w2out)
{
  const int bid = blockIdx.x;
  if (bid < 192) {
    int z = bid >> 4, rem = bid & 15;
    int bx = rem & 3, by = rem >> 2;
    long long so = ((long long)bx * 12 + z) * C;
    g128_body(xb, Wct + (long long)z * C * C, bc + (long long)z * C,
              nullptr, hb + (long long)z * M_BD * C, ps + so, pq + so,
              M_BD, C, C, C, C, C, bx, by);
  } else if (bid < 276) {
    int local = bid - 192;
    gemm64_body(xb, kvwt, kvbias, nullptr, kxvx_b, M_BD, 768, C, C, C, 768, 1,
                local % 7, local / 7);
  } else {
    int local = bid - 276;
    gemm64_body(epwt, armwvb, nullptr, nullptr, w2out, C, C, C, C, C, C, 1,
                local % 8, local / 8);
  }
}

// ---------------- Sc (128² body, bf16 out) + Gm (64² body, bf16 out) ----------------
__global__ __launch_bounds__(256)
void scgm_k(const unsigned short* __restrict__ qkvfe, unsigned short* __restrict__ Sc16,
            unsigned short* __restrict__ Gm16)
{
  const int bid = blockIdx.x;
  if (bid < 200) {
    int z = bid / 25, rem = bid % 25;
    g128_body(qkvfe + (long long)z * 588 * 1024, qkvfe + 256 + (long long)z * 588 * 1024,
              nullptr, nullptr, Sc16 + (long long)z * 588 * 588, nullptr, nullptr,
              588, 588, H, 1024, 1024, 588, rem % 5, rem / 5);
  } else {
    int z = bid - 200;
    const unsigned short* vp = qkvfe + 512 + (long long)z * 49 * 1024;
    gemm64_body(vp, vp, nullptr, nullptr, Gm16 + (long long)z * 2401,
                D, D, C, 1024, 1024, D, 1, 0, 0);
  }
}

// ------- f_u = relu(norm(h_bf16)) -> bf16, f_v = mean_d f_u (4-slice stats fold) -------
__global__ __launch_bounds__(256)
void fu_fv(const unsigned short* __restrict__ hb, const float* __restrict__ ps,
           const float* __restrict__ pq, unsigned short* __restrict__ fub,
           float* __restrict__ fv)
{
  const int bid = blockIdx.x;
  const int b = bid / N, n = bid % N;
  const int c = blockIdx.y * 256 + threadIdx.x;
  const int idx = n * C + c;
  float s = 0.f, q = 0.f;
#pragma unroll
  for (int sl = 0; sl < 4; ++sl) { s += ps[sl * (N * C) + idx]; q += pq[sl * (N * C) + idx]; }
  float m = s / (float)M_BD;
  float rv = rsqrtf(q / (float)M_BD - m * m + BN_EPS);
  float acc = 0.f;
  for (int d = 0; d < D; ++d) {
    float v = bf2f(hb[((long long)n * M_BD + b * D + d) * C + c]);
    v = fmaxf((v - m) * rv, 0.f);
    fub[((long long)bid * D + d) * C + c] = f2bf(v);
    acc += v;
  }
  fv[(long long)bid * C + c] = acc * (1.0f / (float)D);
}

// -- fused: fam softmax (0..18) + vx transpose (19..82) + cosine mask (83..90) --
__global__ __launch_bounds__(256)
void softvxt_k(const float* __restrict__ Sf, unsigned short* __restrict__ Ppb,
               const unsigned short* __restrict__ kvx, unsigned short* __restrict__ vxtb,
               const float* __restrict__ fv, float* __restrict__ maskp)
{
  const int tid = threadIdx.x;
  if (blockIdx.x < 19) {
    int row = blockIdx.x * 256 + tid;
    if (row >= M_BND) return;
    const float* p = Sf + (long long)row * 49;
    float v[49];
    float m = -1e30f;
#pragma unroll
    for (int j = 0; j < 49; ++j) { v[j] = p[j] * ATT_SCALE; m = fmaxf(m, v[j]); }
    float s = 0.f;
#pragma unroll
    for (int j = 0; j < 49; ++j) { v[j] = __expf(v[j] - m); s += v[j]; }
    float inv = 1.f / s;
    unsigned short* o = Ppb + (long long)row * 64;
#pragma unroll
    for (int j = 0; j < 49; ++j) o[j] = f2bf(v[j] * inv);
#pragma unroll
    for (int j = 49; j < 64; ++j) o[j] = 0;
    return;
  }
  if (blockIdx.x < 83) {
    const int i = blockIdx.x - 19;
    const int b = i >> 3, cc = i & 7;
    __shared__ unsigned short t[49][65];
    for (int idx = tid; idx < 49 * 64; idx += 256) {
      int rr = idx >> 6, k = idx & 63;
      t[rr][k] = kvx[(long long)(b * 49 + rr) * 768 + 256 + cc * 64 + k];
    }
    __syncthreads();
    for (int idx = tid; idx < 64 * 64; idx += 256) {
      int n = idx >> 6, kk = idx & 63;
      vxtb[((long long)b * 512 + cc * 64 + n) * 64 + kk] = (kk < 49) ? t[kk][n] : (unsigned short)0;
    }
    return;
  }
  const int b = blockIdx.x - 83;
  __shared__ float fl[N][C];
  __shared__ float adj[N][N];
  __shared__ float nrm[N];
  __shared__ float dis[N];
  for (int idx = tid; idx < N * C; idx += 256)
    fl[idx / C][idx % C] = fv[(long long)b * N * C + idx];
  __syncthreads();
  if (tid < N * N) {
    int i = tid / N, j = tid % N;
    float s = 0.f;
    for (int k = 0; k < C; ++k) s += fl[i][k] * fl[j][k];
    adj[i][j] = s;
  }
  __syncthreads();
  if (tid < N) nrm[tid] = fmaxf(sqrtf(adj[tid][tid]), 1e-12f);
  __syncthreads();
  if (tid < N * N) {
    int i = tid / N, j = tid % N;
    adj[i][j] = adj[i][j] / (nrm[i] * nrm[j]);
  }
  __syncthreads();
  if (tid < N) {
    float s = 0.f;
    for (int j = 0; j < N; ++j) s += adj[tid][j];
    dis[tid] = rsqrtf(s);
  }
  __syncthreads();
  if (tid < N * N) {
    int i = tid / N, j = tid % N;
    maskp[b * E + tid] = adj[i][j] * dis[i] * dis[j];
  }
}

// ------- edge finish: softmax + colsum@V (S1, 2-wide) + st2 = <A^T A, G> via MFMA -------
__global__ __launch_bounds__(256)
void edge_finish(const unsigned short* __restrict__ Sc16, const unsigned short* __restrict__ G16,
                 const unsigned short* __restrict__ qkvfe,
                 float* __restrict__ S1, float* __restrict__ eS)
{
  const int bid = blockIdx.x;           // b*E + e
  const int b = bid / E, e = bid % E;
  const int i = e / N, j = e % N;
  const unsigned short* Scb = Sc16 + (long long)b * 588 * 588 + (long long)(j * 49) * 588 + i * 49;
  const unsigned short* Gp  = G16 + (long long)(b * N + i) * 2401;
  const unsigned short* Vp = qkvfe + (long long)(b * N + i) * D * 1024 + 512;

  __shared__ float aT[49][53];          // aT[dj][di] = probs[di][dj]
  __shared__ float g[49][53];
  __shared__ unsigned short abT[64][72];
  __shared__ float ws[52];
  __shared__ float r0[4], r1[4];
  const int tid = threadIdx.x;
  const int wid = tid >> 6, lane = tid & 63;
  const int lr = lane & 15, lg = lane >> 4;

  for (int idx = tid; idx < 49 * 49; idx += 256) {
    int di = idx / 49, dj = idx - di * 49;
    aT[dj][di] = bf2f(Scb[di * 588 + dj]) * ATT_SCALE;
    g[di][dj] = bf2f(Gp[idx]);
  }
  __syncthreads();
  if (tid < D) {
    float m = -1e30f;
    for (int jj = 0; jj < D; ++jj) m = fmaxf(m, aT[jj][tid]);
    float s = 0.f;
    for (int jj = 0; jj < D; ++jj) { float ev = __expf(aT[jj][tid] - m); aT[jj][tid] = ev; s += ev; }
    float inv = 1.f / s;
    for (int jj = 0; jj < D; ++jj) aT[jj][tid] *= inv;
  }
  __syncthreads();
  for (int idx = tid; idx < 64 * 64; idx += 256) {
    int dj = idx >> 6, di = idx & 63;
    float v = (dj < D && di < D) ? aT[dj][di] : 0.f;
    abT[dj][di] = f2bf(v);
  }
  if (tid < D) {
    float s = 0.f;
    for (int di = 0; di < D; ++di) s += aT[tid][di];
    ws[tid] = s;
  }
  __syncthreads();

  floatx4 acc[4];
#pragma unroll
  for (int tk = 0; tk < 4; ++tk) acc[tk] = floatx4{0.f,0.f,0.f,0.f};
  shortx8 af0 = *reinterpret_cast<const shortx8*>(&abT[wid * 16 + lr][lg * 8]);
  shortx8 af1 = *reinterpret_cast<const shortx8*>(&abT[wid * 16 + lr][32 + lg * 8]);
#pragma unroll
  for (int tk = 0; tk < 4; ++tk) {
    shortx8 bf0v = *reinterpret_cast<const shortx8*>(&abT[tk * 16 + lr][lg * 8]);
    shortx8 bf1v = *reinterpret_cast<const shortx8*>(&abT[tk * 16 + lr][32 + lg * 8]);
    acc[tk] = __builtin_amdgcn_mfma_f32_16x16x32_bf16(af0, bf0v, acc[tk], 0, 0, 0);
    acc[tk] = __builtin_amdgcn_mfma_f32_16x16x32_bf16(af1, bf1v, acc[tk], 0, 0, 0);
  }
  float st2 = 0.f;
#pragma unroll
  for (int tk = 0; tk < 4; ++tk) {
    int kcol = tk * 16 + lr;
#pragma unroll
    for (int rg = 0; rg < 4; ++rg) {
      int jrow = wid * 16 + lg * 4 + rg;
      if (jrow < D && kcol < D) st2 = fmaf(acc[tk][rg], g[jrow][kcol], st2);
    }
  }

  // S1 = colsum(A) @ V  — 2 bf16 per lane per row
  const unsigned* Vp32 = reinterpret_cast<const unsigned*>(Vp);
  float s1a = 0.f, s1b = 0.f;
  for (int dk = 0; dk < D; ++dk) {
    unsigned u = Vp32[dk * 512 + tid];
    float w = ws[dk];
    s1a = fmaf(w, bf2f((unsigned short)(u & 0xffffu)), s1a);
    s1b = fmaf(w, bf2f((unsigned short)(u >> 16)), s1b);
  }
  S1[(long long)bid * C + 2 * tid]     = s1a;
  S1[(long long)bid * C + 2 * tid + 1] = s1b;
  float st = s1a + s1b;

  for (int off = 32; off; off >>= 1) { st += __shfl_down(st, off); st2 += __shfl_down(st2, off); }
  if (lane == 0) { r0[wid] = st; r1[wid] = st2; }
  __syncthreads();
  if (tid == 0) {
    eS[bid * 2 + 0] = r0[0] + r0[1] + r0[2] + r0[3];
    eS[bid * 2 + 1] = r1[0] + r1[1] + r1[2] + r1[3];
  }
}

// ------- f_e = (S1/D - me)*rve * mask; also writes bf16 copy for GEMM A -------
__global__ __launch_bounds__(256)
void fe_k(const float* __restrict__ S1, const float* __restrict__ eS,
          const float* __restrict__ maskp, float* __restrict__ fe,
          unsigned short* __restrict__ feb)
{
  __shared__ float csh[3];
  long long idx0 = (long long)blockIdx.x * 256;
  long long be = idx0 / C;
  int e = (int)(be % E);
  if (threadIdx.x == 0) {
    float s = 0.f, q = 0.f;
    for (int b = 0; b < B; ++b) { s += eS[(b * E + e) * 2]; q += eS[(b * E + e) * 2 + 1]; }
    const float inv = 1.f / (float)(B * D * C);
    float m = s * inv;
    csh[0] = m;
    csh[1] = rsqrtf(q * inv - m * m + BN_EPS);
    csh[2] = maskp[be];
  }
  __syncthreads();
  long long idx = idx0 + threadIdx.x;
  float v = (S1[idx] * (1.0f / (float)D) - csh[0]) * csh[1] * csh[2];
  fe[idx] = v;
  feb[idx] = f2bf(v);
}

// ------- GNN layer GEMMs: blocks 0..35 EW (128² gload), 36..99 ABUV (64²) -------
__global__ __launch_bounds__(256)
void gnn_gemm_k(const unsigned short* __restrict__ feb, const unsigned short* __restrict__ wet,
                float* __restrict__ EW, const float* __restrict__ fv,
                const unsigned short* __restrict__ ABUVt, float* __restrict__ ABUV)
{
  const int bid = blockIdx.x;
  if (bid < 36) {
    g128_body(feb, wet, nullptr, EW, nullptr, nullptr, nullptr,
              B * E, C, C, C, C, C, bid % 9, bid / 9);
  } else {
    int local = bid - 36;
    gemm64_body(fv, ABUVt, nullptr, ABUV, nullptr,
                B * N, 2048, C, C, C, 2048, 0, local % 2, local / 2);
  }
}

// ---------------- GNN: BN stats per e over agg = A[i]+B[j]+EW[e] ----------------
__global__ __launch_bounds__(256)
void agg_stats(const float* __restrict__ ABUV, const float* __restrict__ EW,
               float* __restrict__ mu_e, float* __restrict__ rs_e)
{
  const int e = blockIdx.x;
  const int i = e / N, j = e % N;
  const int tid = threadIdx.x;
  float s = 0.f, q = 0.f;
  for (int idx = tid; idx < B * C; idx += 256) {
    int b = idx >> 9, c = idx & 511;
    float v = ABUV[(long long)(b * N + i) * 2048 + c]
            + ABUV[(long long)(b * N + j) * 2048 + 512 + c]
            + EW[((long long)b * E + e) * C + c];
    s += v; q += v * v;
  }
  for (int off = 32; off; off >>= 1) { s += __shfl_down(s, off); q += __shfl_down(q, off); }
  __shared__ float r0[4], r1[4];
  int wid = tid >> 6, lane = tid & 63;
  if (lane == 0) { r0[wid] = s; r1[wid] = q; }
  __syncthreads();
  if (tid == 0) {
    float ss = r0[0] + r0[1] + r0[2] + r0[3];
    float qq = r1[0] + r1[1] + r1[2] + r1[3];
    float m = ss / (float)(B * C);
    mu_e[e] = m;
    rs_e[e] = rsqrtf(qq / (float)(B * C) - m * m + BN_EPS);
  }
}

// -- fused: ed update (+bf16 copy) + sigmoid/softmax msg + pre + node-BN partials --
__global__ __launch_bounds__(256)
void edmsg_k(float* __restrict__ fe, unsigned short* __restrict__ feb,
             const float* __restrict__ ABUV,
             const float* __restrict__ EW, const float* __restrict__ mu_e,
             const float* __restrict__ rs_e, float* __restrict__ pre,
             float* __restrict__ nps, float* __restrict__ npq)
{
  const int bid = blockIdx.x;
  const int b = bid / N, i = bid % N;
  const int tid = threadIdx.x;
  float ls = 0.f, lq = 0.f;
  for (int c = tid; c < C; c += 256) {
    float ai = ABUV[(long long)(b * N + i) * 2048 + c];
    float sv[N];
    float m = -1e30f;
#pragma unroll
    for (int jn = 0; jn < N; ++jn) {
      int e = i * N + jn;
      float v = ai + ABUV[(long long)(b * N + jn) * 2048 + 512 + c]
              + EW[((long long)b * E + e) * C + c];
      v = (v - mu_e[e]) * rs_e[e];
      long long fidx = ((long long)b * E + e) * C + c;
      float ed = fe[fidx] + fmaxf(v, 0.f);
      fe[fidx] = ed;
      feb[fidx] = f2bf(ed);
      float sg = 1.f / (1.f + __expf(-ed));
      sv[jn] = sg; m = fmaxf(m, sg);
    }
    float sum = 0.f;
#pragma unroll
    for (int jn = 0; jn < N; ++jn) { float ev = __expf(sv[jn] - m); sv[jn] = ev; sum += ev; }
    float acc = 0.f;
#pragma unroll
    for (int jn = 0; jn < N; ++jn)
      acc = fmaf(sv[jn], ABUV[(long long)(b * N + jn) * 2048 + 1536 + c], acc);
    acc /= (sum * (float)N);
    float pv = ABUV[(long long)bid * 2048 + 1024 + c] + acc;
    pre[(long long)bid * C + c] = pv;
    ls += pv; lq += pv * pv;
  }
  for (int off = 32; off; off >>= 1) { ls += __shfl_down(ls, off); lq += __shfl_down(lq, off); }
  __shared__ float r0[4], r1[4];
  int wid = tid >> 6, lane = tid & 63;
  if (lane == 0) { r0[wid] = ls; r1[wid] = lq; }
  __syncthreads();
  if (tid == 0) {
    nps[i * B + b] = r0[0] + r0[1] + r0[2] + r0[3];
    npq[i * B + b] = r1[0] + r1[1] + r1[2] + r1[3];
  }
}

__global__ void xv_update(float* __restrict__ xv, const float* __restrict__ pre,
                          const float* __restrict__ nps, const float* __restrict__ npq)
{
  long long idx = (long long)blockIdx.x * 256 + threadIdx.x;
  if (idx >= (long long)B * N * C) return;
  int i = (int)((idx / C) % N);
  float s = 0.f, q = 0.f;
#pragma unroll
  for (int bb = 0; bb < B; ++bb) { s += nps[i * B + bb]; q += npq[i * B + bb]; }
  float mu = s * (1.f / (float)(B * C));
  float rs = rsqrtf(q * (1.f / (float)(B * C)) - mu * mu + BN_EPS);
  float v = xv[idx] + (pre[idx] - mu) * rs;
  xv[idx] = fmaxf(v, 0.f);
}

// ------- outputs (final node update folded into cl part) -------
__global__ __launch_bounds__(256)
void out_k(const float* __restrict__ xv, const float* __restrict__ pre,
           const float* __restrict__ nps, const float* __restrict__ npq,
           const float* __restrict__ sc,
           const float* __restrict__ ed, const float* __restrict__ w,
           const float* __restrict__ bias, float* __restrict__ out)
{
  const int bid = blockIdx.x;
  const int tid = threadIdx.x;
  int wid = tid >> 6, lane = tid & 63;
  if (bid < B * N) {
    const int b = bid / N, i = bid % N;
    float s = 0.f, q = 0.f;
#pragma unroll
    for (int t = 0; t < B; ++t) { s += nps[i * B + t]; q += npq[i * B + t]; }
    float mu = s * (1.f / (float)(B * C));
    float rs = rsqrtf(q * (1.f / (float)(B * C)) - mu * mu + BN_EPS);
    float sxx = 0.f, sss = 0.f, sxs = 0.f;
    for (int c = tid; c < C; c += 256) {
      float xvv = fmaxf(xv[(long long)bid * C + c] + (pre[(long long)bid * C + c] - mu) * rs, 0.f);
      float scv = fmaxf(sc[i * C + c], 0.f);
      sxx += xvv * xvv; sss += scv * scv; sxs += xvv * scv;
    }
    for (int off = 32; off; off >>= 1) {
      sxx += __shfl_down(sxx, off);
      sss += __shfl_down(sss, off);
      sxs += __shfl_down(sxs, off);
    }
    __shared__ float r0[4], r1[4], r2[4];
    if (lane == 0) { r0[wid] = sxx; r1[wid] = sss; r2[wid] = sxs; }
    __syncthreads();
    if (tid == 0) {
      float a = r0[0] + r0[1] + r0[2] + r0[3];
      float ss = r1[0] + r1[1] + r1[2] + r1[3];
      float p = r2[0] + r2[1] + r2[2] + r2[3];
      float nx = fmaxf(sqrtf(a), 1e-12f);
      float ns = fmaxf(sqrtf(ss), 1e-12f);
      out[b * N + i] = p / (nx * ns);
    }
  } else {
    const int eb = bid - B * N;
    float a0 = 0, a1 = 0, a2 = 0, a3 = 0;
    for (int c = tid; c < C; c += 256) {
      float v = ed[(long long)eb * C + c];
      a0 = fmaf(v, w[c * 4 + 0], a0);
      a1 = fmaf(v, w[c * 4 + 1], a1);
      a2 = fmaf(v, w[c * 4 + 2], a2);
      a3 = fmaf(v, w[c * 4 + 3], a3);
    }
    for (int off = 32; off; off >>= 1) {
      a0 += __shfl_down(a0, off);
      a1 += __shfl_down(a1, off);
      a2 += __shfl_down(a2, off);
      a3 += __shfl_down(a3, off);
    }
    __shared__ float r[4][4];
    if (lane == 0) { r[wid][0] = a0; r[wid][1] = a1; r[wid][2] = a2; r[wid][3] = a3; }
    __syncthreads();
    if (tid < 4) {
      float sr = r[0][tid] + r[1][tid] + r[2][tid] + r[3][tid];
      out[B * N + eb * 4 + tid] = sr + bias[tid];
    }
  }
}

} // namespace

extern "C" void kernel_launch(void* const* d_in, const int* in_sizes, int n_in,
                              void* d_out, int out_size, void* d_ws, size_t ws_size,
                              hipStream_t stream)
{
  (void)in_sizes; (void)n_in; (void)out_size; (void)ws_size;
  const float* x      = (const float*)d_in[0];
  const float* Wc     = (const float*)d_in[1];
  const float* bc     = (const float*)d_in[2];
  const float* fam_wq = (const float*)d_in[3];
  const float* fam_bq = (const float*)d_in[4];
  const float* fam_wk = (const float*)d_in[5];
  const float* fam_bk = (const float*)d_in[6];
  const float* fam_wv = (const float*)d_in[7];
  const float* fam_bv = (const float*)d_in[8];
  const float* arm_wq = (const float*)d_in[9];
  const float* arm_bq = (const float*)d_in[10];
  const float* arm_wk = (const float*)d_in[11];
  const float* arm_bk = (const float*)d_in[12];
  const float* arm_wv = (const float*)d_in[13];
  const float* arm_bv = (const float*)d_in[14];
  const float* ep_w   = (const float*)d_in[15];
  const float* ep_b   = (const float*)d_in[16];
  const float* gw[10] = {
    (const float*)d_in[17], (const float*)d_in[18], (const float*)d_in[19],
    (const float*)d_in[20], (const float*)d_in[21],
    (const float*)d_in[22], (const float*)d_in[23], (const float*)d_in[24],
    (const float*)d_in[25], (const float*)d_in[26]};
  const float* sc     = (const float*)d_in[27];
  const float* efc_w  = (const float*)d_in[28];
  const float* efc_b  = (const float*)d_in[29];
  float* out = (float*)d_out;

  char* wsb = (char*)d_ws;
  size_t off = 0;
  auto allocf = [&](size_t n) { float* p = (float*)(wsb + off); off += ((n * 4 + 255) / 256) * 256; return p; };
  auto allocu = [&](size_t n) { unsigned short* p = (unsigned short*)(wsb + off); off += ((n * 2 + 255) / 256) * 256; return p; };

  float* bnp_s = allocf(24576);            // 4 slices x N x C
  float* bnp_q = allocf(24576);
  float* f_v   = allocf(49152);
  float* Sf    = allocf(230496);           // 8*588*49
  float* S1    = allocf(589824);
  float* fe    = allocf(589824);
  float* EW    = allocf(589824);
  float* eS    = allocf(2304);
  float* mask  = allocf(1152);
  float* ABUV  = allocf(196608);
  float* pre   = allocf(49152);
  float* mu_e  = allocf(144);
  float* rs_e  = allocf(144);
  float* nps   = allocf(96);
  float* npq   = allocf(96);
  float* kvbias  = allocf(768);
  float* qkvbias = allocf(1024);           // [arm_bq|arm_bk|b2]

  unsigned short* Wct    = allocu(3145728);
  unsigned short* famqt  = allocu(131072);
  unsigned short* kvwt   = allocu(393216);   // [768][512]: fam_wk | fam_wv
  unsigned short* qkw2t  = allocu(524288);   // [1024][512]: arm_wq | arm_wk | W2^T
  unsigned short* epwt   = allocu(262144);
  unsigned short* armwvb = allocu(262144);   // arm_wv row-major bf16
  unsigned short* wet0   = allocu(262144);
  unsigned short* wet1   = allocu(262144);
  unsigned short* ABUVt0 = allocu(1048576);
  unsigned short* ABUVt1 = allocu(1048576);
  unsigned short* xb     = allocu(262144);   // [512][512] (rows padded for gload)
  unsigned short* hb     = allocu(2408448);  // h bf16 [12][392][512]
  unsigned short* fub    = allocu(2408448);
  unsigned short* q1b    = allocu(1204224);  // [4704][256]
  unsigned short* kxvx_b = allocu(350208);   // [456][768] (pad rows for B overread)
  unsigned short* Ppb    = allocu(301056);   // [4704][64]
  unsigned short* vxtb   = allocu(262144);   // [8][512][64]
  unsigned short* featb  = allocu(2424832);  // [4736][512] (rows padded for gload)
  unsigned short* qkvfe  = allocu(4915200);  // [4800][1024]: q|k|vfe (pad rows)
  unsigned short* feb    = allocu(589824);   // fe bf16 [1152][512]
  unsigned short* Sc16   = allocu(2765952);  // [8][588][588] bf16
  unsigned short* Gm16   = allocu(230496);   // [96][49][49] bf16

  dim3 blk(256);

  // -------- weight transpose+cast (28 jobs) + castrow/bias/b2 branch (z=28) --------
  TCJobs tj{};
  int jn = 0;
  for (int n = 0; n < 12; ++n) { tj.src[jn] = Wc + (size_t)n * C * C; tj.dst[jn] = Wct + (size_t)n * C * C; tj.nn[jn] = C; ++jn; }
  tj.src[jn] = fam_wq; tj.dst[jn] = famqt;             tj.nn[jn] = H; ++jn;
  tj.src[jn] = fam_wk; tj.dst[jn] = kvwt;              tj.nn[jn] = H; ++jn;
  tj.src[jn] = fam_wv; tj.dst[jn] = kvwt + 256 * 512;  tj.nn[jn] = C; ++jn;
  tj.src[jn] = arm_wq; tj.dst[jn] = qkw2t;             tj.nn[jn] = H; ++jn;
  tj.src[jn] = arm_wk; tj.dst[jn] = qkw2t + 256 * 512; tj.nn[jn] = H; ++jn;
  tj.src[jn] = ep_w;   tj.dst[jn] = epwt;              tj.nn[jn] = C; ++jn;
  tj.src[jn] = gw[2];  tj.dst[jn] = wet0;              tj.nn[jn] = C; ++jn;
  tj.src[jn] = gw[7];  tj.dst[jn] = wet1;              tj.nn[jn] = C; ++jn;
  tj.src[jn] = gw[0];  tj.dst[jn] = ABUVt0;               tj.nn[jn] = C; ++jn;
  tj.src[jn] = gw[1];  tj.dst[jn] = ABUVt0 + 1 * C * C;   tj.nn[jn] = C; ++jn;
  tj.src[jn] = gw[3];  tj.dst[jn] = ABUVt0 + 2 * C * C;   tj.nn[jn] = C; ++jn;
  tj.src[jn] = gw[4];  tj.dst[jn] = ABUVt0 + 3 * C * C;   tj.nn[jn] = C; ++jn;
  tj.src[jn] = gw[5];  tj.dst[jn] = ABUVt1;               tj.nn[jn] = C; ++jn;
  tj.src[jn] = gw[6];  tj.dst[jn] = ABUVt1 + 1 * C * C;   tj.nn[jn] = C; ++jn;
  tj.src[jn] = gw[8];  tj.dst[jn] = ABUVt1 + 2 * C * C;   tj.nn[jn] = C; ++jn;
  tj.src[jn] = gw[9];  tj.dst[jn] = ABUVt1 + 3 * C * C;   tj.nn[jn] = C; ++jn;
  tcast_k<<<dim3(16, 16, 29), blk, 0, stream>>>(tj, x, xb, arm_wv, armwvb,
      fam_bk, fam_bv, arm_bq, arm_bk, arm_bv, ep_w, ep_b, kvbias, qkvbias);

  // mega: h (BN stats fused) | fam k|v | W2^T
  proj1_k<<<dim3(340), blk, 0, stream>>>(xb, Wct, bc, hb, bnp_s, bnp_q,
      kvwt, kvbias, kxvx_b, epwt, armwvb, qkw2t + 512 * 512);
  fu_fv<<<dim3(B * N, 2), blk, 0, stream>>>(hb, bnp_s, bnp_q, fub, f_v);

  // q1 = f_u @ fam_wq
  gemm_mfma<<<dim3(74, 4, 1), blk, 0, stream>>>(fub, famqt, fam_bq, nullptr, q1b,
      M_BND, H, C, C, C, H, 1, 0, 0, 0, 0);
  // Sf[b] = q1[b] @ kx[b]^T  (588 x 49)
  gemm_mfma<<<dim3(10, 1, 8), blk, 0, stream>>>(q1b, kxvx_b, nullptr, Sf, nullptr,
      588, 49, H, H, 768, 49, 1, 588LL * 256, 49LL * 768, 0LL, 588LL * 49);
  softvxt_k<<<dim3(91), blk, 0, stream>>>(Sf, Ppb, kxvx_b, vxtb, f_v, mask);
  // feat[b] = P[b] @ vx[b]  (588 x 512, K=64)
  gemm_mfma<<<dim3(10, 8, 8), blk, 0, stream>>>(Ppb, vxtb, nullptr, nullptr, featb,
      588, C, 64, 64, 64, C, 1, 588LL * 64, 512LL * 64, 0LL, 588LL * 512);

  // merged arm q|k|vfe projection
  gemm128g<<<dim3(37, 8, 1), blk, 0, stream>>>(featb, qkw2t, qkvbias, nullptr, qkvfe,
      nullptr, nullptr, M_BND, 1024, C, C, C, 1024, 0, 0, 0, 0);

  // Sc[b] = qf[b] @ kf[b]^T (bf16 out) + G[node] = vfe vfe^T (bf16 out), one launch
  scgm_k<<<dim3(296), blk, 0, stream>>>(qkvfe, Sc16, Gm16);

  // per-edge: softmax + colsum@V (S1) + st2 via MFMA
  edge_finish<<<dim3(B * E), blk, 0, stream>>>(Sc16, Gm16, qkvfe, S1, eS);
  fe_k<<<dim3(2304), blk, 0, stream>>>(S1, eS, mask, fe, feb);

  // two GNN layers (final node update folded into out_k)
  for (int L = 0; L < 2; ++L) {
    const unsigned short* ABUVt = L ? ABUVt1 : ABUVt0;
    const unsigned short* wet   = L ? wet1 : wet0;
    gnn_gemm_k<<<dim3(100), blk, 0, stream>>>(feb, wet, EW, f_v, ABUVt, ABUV);
    agg_stats<<<dim3(E), blk, 0, stream>>>(ABUV, EW, mu_e, rs_e);
    edmsg_k<<<dim3(B * N), blk, 0, stream>>>(fe, feb, ABUV, EW, mu_e, rs_e, pre, nps, npq);
    if (L == 0)
      xv_update<<<dim3((B * N * C + 255) / 256), blk, 0, stream>>>(f_v, pre, nps, npq);
  }

  out_k<<<dim3(B * N + B * E), blk, 0, stream>>>(f_v, pre, nps, npq, sc, fe, efc_w, efc_b, out);
}